// Round 1
// baseline (625.425 us; speedup 1.0000x reference)
//
#include <hip/hip_runtime.h>
#include <hip/hip_bf16.h>

#define N_NODES 100000
#define N_EDGES 3200000
#define NGRAPH 1024
#define KTOP 30
#define PELEM (NGRAPH * KTOP * 97)         // pooled tensor elements

#define NBKT 782                            // ceil(100000 / 128) node buckets
#define NTILE 391                           // edge tiles
#define TILE 8192                           // edges per tile (391*8192 >= 3.2M)
#define BKT_CAP 4736                        // padded bucket capacity (mean 4096 + 10 sigma)

typedef __hip_bfloat16 bf16;

__device__ __forceinline__ float u2f(unsigned short h) {
    return __uint_as_float(((unsigned int)h) << 16);
}
// Flag-steered scalar load of a float-tensor input that may be bf16 or f32.
__device__ __forceinline__ float LD(const void* p, int i, int bf) {
    if (bf) return u2f(((const unsigned short*)p)[i]);
    return ((const float*)p)[i];
}

// ---------- dtype probe ----------
__global__ void k_detect(const void* w1, int* flag) {
    if (threadIdx.x == 0 && blockIdx.x == 0) {
        const unsigned short* u = (const unsigned short*)w1;
        int plausible = 0;
        for (int i = 0; i < 64; i++) {
            float a = fabsf(u2f(u[2 * i]));
            if (a == 0.f || (a >= 9.765625e-4f && a <= 2.0f)) plausible++;
        }
        *flag = (plausible >= 40) ? 1 : 0;
    }
}

// ---------- one-pass padded-bucket edge partition ----------
// cur[b] pre-init to b*BKT_CAP; tiles reserve contiguous ranges per bucket
// via one global atomicAdd per (tile,bucket). Records packed 24-bit:
// (dst&127)<<17 | src. Bucket padding is never read downstream (rs/re).
__global__ void k_icur(int* __restrict__ cur) {
    int i = blockIdx.x * 256 + threadIdx.x;
    if (i < NBKT) cur[i] = i * BKT_CAP;
}

__global__ __launch_bounds__(256) void k_scat(const int* __restrict__ src,
                                              const int* __restrict__ dst,
                                              int* __restrict__ cur,
                                              int* __restrict__ ebuf) {
    __shared__ int pk[TILE];                 // 32 KB packed records
    __shared__ unsigned short bk[TILE];      // 16 KB bucket ids (0xFFFF = skip)
    __shared__ int h[NBKT];                  // per-tile histogram, then cursor
    __shared__ int base[NBKT];               // reserved global base per bucket
    int tid = threadIdx.x;
    int ebase = blockIdx.x * TILE;
    for (int i = tid; i < NBKT; i += 256) h[i] = 0;
    __syncthreads();
    for (int i = tid; i < TILE; i += 256) {
        int e = ebase + i;
        int bkt = 0xFFFF;
        if (e < N_EDGES) {
            int s = __builtin_nontemporal_load(src + e);
            int d = __builtin_nontemporal_load(dst + e);
            if (s != d) {
                bkt = d >> 7;
                pk[i] = ((d & 127) << 17) | s;
                atomicAdd(&h[bkt], 1);
            }
        }
        bk[i] = (unsigned short)bkt;
    }
    __syncthreads();
    for (int i = tid; i < NBKT; i += 256) {
        int c = h[i];
        base[i] = c ? atomicAdd(&cur[i], c) : 0;
    }
    __syncthreads();
    for (int i = tid; i < NBKT; i += 256) h[i] = 0;   // reuse as local cursors
    __syncthreads();
    for (int i = tid; i < TILE; i += 256) {
        int bkt = bk[i];
        if (bkt != 0xFFFF) {
            int p = base[bkt] + atomicAdd(&h[bkt], 1);
            if (p < (bkt + 1) * BKT_CAP) ebuf[p] = pk[i];   // overflow guard (never fires)
        }
    }
}

__global__ __launch_bounds__(256) void k_bcsr(const int* __restrict__ ebuf,
                                              const int* __restrict__ cur,
                                              int* __restrict__ rs,
                                              int* __restrict__ re,
                                              float* __restrict__ dis,
                                              int* __restrict__ csr) {
    __shared__ int dloc[128];
    __shared__ int sc[128];
    int b = blockIdx.x;
    int node0 = b << 7;
    int nn = N_NODES - node0; if (nn > 128) nn = 128;
    int tid = threadIdx.x;
    if (tid < 128) dloc[tid] = 0;
    __syncthreads();
    int s = b * BKT_CAP;
    int cnt = cur[b] - s; if (cnt > BKT_CAP) cnt = BKT_CAP;
    int e = s + cnt;
    for (int i = s + tid; i < e; i += 256)
        atomicAdd(&dloc[ebuf[i] >> 17], 1);
    __syncthreads();
    if (tid < 128) sc[tid] = dloc[tid];
    __syncthreads();
    for (int off = 1; off < 128; off <<= 1) {
        int t = (tid >= off && tid < 128) ? sc[tid - off] : 0;
        __syncthreads();
        if (tid < 128) sc[tid] += t;
        __syncthreads();
    }
    if (tid < nn) {
        int st = s + sc[tid] - dloc[tid];
        rs[node0 + tid] = st;
        re[node0 + tid] = st + dloc[tid];
        dis[node0 + tid] = rsqrtf((float)dloc[tid] + 1.0f);
    }
    __syncthreads();
    if (tid < 128) dloc[tid] = s + sc[tid] - dloc[tid];  // cursors
    __syncthreads();
    for (int i = s + tid; i < e; i += 256) {
        int pv = __builtin_nontemporal_load(ebuf + i);
        int pos = atomicAdd(&dloc[pv >> 17], 1);
        csr[pos] = pv & 0x1FFFF;
    }
}

__global__ void k_gstart(const int* __restrict__ batch, int* __restrict__ gstart) {
    int g = blockIdx.x * 256 + threadIdx.x;
    if (g > NGRAPH) return;
    int lo = 0, hi = N_NODES;
    while (lo < hi) {
        int mid = (lo + hi) >> 1;
        if (batch[mid] < g) lo = mid + 1; else hi = mid;
    }
    gstart[g] = lo;
}

// ---------- GCN layers (activations f32; ts = dis * (x @ W)) ----------
__global__ __launch_bounds__(256) void k_mm1(const void* __restrict__ x,
                                             const void* __restrict__ w,
                                             const int* __restrict__ flagp,
                                             const float* __restrict__ dis,
                                             float* __restrict__ ts) {
    __shared__ float Wl[128 * 32];
    __shared__ float Xs[32][128];
    int bf = *flagp;
    int tid = threadIdx.x;
    int nbase = blockIdx.x * 32;          // N_NODES % 32 == 0: always full
    if (bf) {
        const ushort4* wv = (const ushort4*)w;
        for (int idx = tid; idx < 1024; idx += 256) {
            ushort4 h = wv[idx];
            int p = idx * 4;
            Wl[p] = u2f(h.x); Wl[p + 1] = u2f(h.y); Wl[p + 2] = u2f(h.z); Wl[p + 3] = u2f(h.w);
        }
        const ushort4* xv = (const ushort4*)x;
        for (int idx = tid; idx < 1024; idx += 256) {
            int nd = idx >> 5, q = idx & 31;
            ushort4 h = xv[(size_t)(nbase + nd) * 32 + q];
            float* d = &Xs[nd][q * 4];
            d[0] = u2f(h.x); d[1] = u2f(h.y); d[2] = u2f(h.z); d[3] = u2f(h.w);
        }
    } else {
        const float* wf = (const float*)w;
        for (int idx = tid; idx < 4096; idx += 256) Wl[idx] = wf[idx];
        const float* xf = (const float*)x;
        for (int idx = tid; idx < 4096; idx += 256)
            Xs[idx >> 7][idx & 127] = xf[(size_t)nbase * 128 + idx];
    }
    __syncthreads();
    int grp = tid >> 5, col = tid & 31;
    for (int rep = 0; rep < 4; rep++) {
        int sub = grp + 8 * rep;
        int node = nbase + sub;
        float acc = 0.f;
#pragma unroll 8
        for (int k = 0; k < 128; k++) acc += Xs[sub][k] * Wl[k * 32 + col];
        ts[node * 32 + col] = dis[node] * acc;
    }
}

__global__ __launch_bounds__(256) void k_mm32(const float* __restrict__ xin,
                                              const void* __restrict__ w,
                                              const int* __restrict__ flagp,
                                              const float* __restrict__ dis,
                                              float* __restrict__ ts) {
    __shared__ float Wl[32 * 32];
    __shared__ float Xs[32][32];
    int bf = *flagp;
    int tid = threadIdx.x;
    int nbase = blockIdx.x * 32;
    if (bf) {
        const ushort4* wv = (const ushort4*)w;
        for (int idx = tid; idx < 256; idx += 256) {
            ushort4 h = wv[idx];
            int p = idx * 4;
            Wl[p] = u2f(h.x); Wl[p + 1] = u2f(h.y); Wl[p + 2] = u2f(h.z); Wl[p + 3] = u2f(h.w);
        }
    } else {
        const float* wf = (const float*)w;
        for (int idx = tid; idx < 1024; idx += 256) Wl[idx] = wf[idx];
    }
    {
        const float4* xv = (const float4*)xin;
        int nd = tid >> 3, q = tid & 7;
        float4 v = xv[(size_t)(nbase + nd) * 8 + q];
        float* d = &Xs[nd][q * 4];
        d[0] = v.x; d[1] = v.y; d[2] = v.z; d[3] = v.w;
    }
    __syncthreads();
    int grp = tid >> 5, col = tid & 31;
    for (int rep = 0; rep < 4; rep++) {
        int sub = grp + 8 * rep;
        int node = nbase + sub;
        float acc = 0.f;
#pragma unroll
        for (int k = 0; k < 32; k++) acc += Xs[sub][k] * Wl[k * 32 + col];
        ts[node * 32 + col] = dis[node] * acc;
    }
}

__global__ __launch_bounds__(256) void k_mm_out1(const float* __restrict__ xin,
                                                 const void* __restrict__ w4,
                                                 const int* __restrict__ flagp,
                                                 const float* __restrict__ dis,
                                                 float* __restrict__ ts4) {
    int node = blockIdx.x * 8 + (threadIdx.x >> 5);
    int lane = threadIdx.x & 31;
    if (node >= N_NODES) return;
    int bf = *flagp;
    float v = xin[node * 32 + lane] * LD(w4, lane, bf);
    for (int off = 16; off; off >>= 1) v += __shfl_down(v, off, 32);
    if (lane == 0) ts4[node] = dis[node] * v;
}

// One wave64 per node; 8 lanes per row (float4/lane); gather loop unrolled x4
// => up to 32 neighbor rows in flight per wave. csr reads are nontemporal so
// the 12.8 MB index stream does not evict ts lines from the per-XCD L2.
__global__ __launch_bounds__(256) void k_agg32(const float4* __restrict__ ts,
                                               const int* __restrict__ rs,
                                               const int* __restrict__ re,
                                               const int* __restrict__ csr,
                                               const float* __restrict__ dis,
                                               const void* __restrict__ b,
                                               const int* __restrict__ flagp,
                                               float4* __restrict__ out) {
    int node = blockIdx.x * 4 + (threadIdx.x >> 6);
    int lane = threadIdx.x & 63;
    int q   = lane & 7;
    int grp = lane >> 3;
    int bf = *flagp;
    int s = rs[node], e = re[node];
    float4 a0 = make_float4(0.f, 0.f, 0.f, 0.f);
    float4 a1 = a0, a2 = a0, a3 = a0;
    int i = s + grp;
    for (; i + 24 < e; i += 32) {
        int v0 = __builtin_nontemporal_load(csr + i);
        int v1 = __builtin_nontemporal_load(csr + i + 8);
        int v2 = __builtin_nontemporal_load(csr + i + 16);
        int v3 = __builtin_nontemporal_load(csr + i + 24);
        float4 m0 = ts[v0 * 8 + q];
        float4 m1 = ts[v1 * 8 + q];
        float4 m2 = ts[v2 * 8 + q];
        float4 m3 = ts[v3 * 8 + q];
        a0.x += m0.x; a0.y += m0.y; a0.z += m0.z; a0.w += m0.w;
        a1.x += m1.x; a1.y += m1.y; a1.z += m1.z; a1.w += m1.w;
        a2.x += m2.x; a2.y += m2.y; a2.z += m2.z; a2.w += m2.w;
        a3.x += m3.x; a3.y += m3.y; a3.z += m3.z; a3.w += m3.w;
    }
    for (; i < e; i += 8) {
        float4 m = ts[__builtin_nontemporal_load(csr + i) * 8 + q];
        a0.x += m.x; a0.y += m.y; a0.z += m.z; a0.w += m.w;
    }
    float4 acc;
    acc.x = (a0.x + a1.x) + (a2.x + a3.x);
    acc.y = (a0.y + a1.y) + (a2.y + a3.y);
    acc.z = (a0.z + a1.z) + (a2.z + a3.z);
    acc.w = (a0.w + a1.w) + (a2.w + a3.w);
#pragma unroll
    for (int off = 8; off < 64; off <<= 1) {
        acc.x += __shfl_xor(acc.x, off);
        acc.y += __shfl_xor(acc.y, off);
        acc.z += __shfl_xor(acc.z, off);
        acc.w += __shfl_xor(acc.w, off);
    }
    if (grp == 0) {
        float4 self = ts[node * 8 + q];
        float d = dis[node];
        float4 r;
        r.x = tanhf(d * (acc.x + self.x) + LD(b, q * 4 + 0, bf));
        r.y = tanhf(d * (acc.y + self.y) + LD(b, q * 4 + 1, bf));
        r.z = tanhf(d * (acc.z + self.z) + LD(b, q * 4 + 2, bf));
        r.w = tanhf(d * (acc.w + self.w) + LD(b, q * 4 + 3, bf));
        out[node * 8 + q] = r;
    }
}

// 16 lanes per node.
__global__ __launch_bounds__(256) void k_agg1(const float* __restrict__ ts4,
                                              const int* __restrict__ rs,
                                              const int* __restrict__ re,
                                              const int* __restrict__ csr,
                                              const float* __restrict__ dis,
                                              const void* __restrict__ b4,
                                              const int* __restrict__ flagp,
                                              float* __restrict__ x4) {
    int node = blockIdx.x * 16 + (threadIdx.x >> 4);
    int lane = threadIdx.x & 15;
    int s = rs[node], e = re[node];
    float acc = 0.f;
    for (int i = s + lane; i < e; i += 16)
        acc += ts4[__builtin_nontemporal_load(csr + i)];
#pragma unroll
    for (int off = 1; off < 16; off <<= 1) acc += __shfl_xor(acc, off);
    if (lane == 0) {
        int bf = *flagp;
        x4[node] = tanhf(dis[node] * (acc + ts4[node]) + LD(b4, 0, bf));
    }
}

// ---------- SortPooling rank ----------
__global__ __launch_bounds__(256) void k_rank(const int* __restrict__ batch,
                                              const int* __restrict__ gstart,
                                              const float* __restrict__ x4,
                                              int* __restrict__ sel) {
    int i = blockIdx.x * 256 + threadIdx.x;
    if (i >= N_NODES) return;
    int g = batch[i];
    int s = gstart[g], e = gstart[g + 1];
    float ki = x4[i];
    int rank = 0;
    for (int j = s; j < e; j++) {
        float kj = x4[j];
        rank += (kj > ki) || (kj == ki && j < i);
    }
    if (rank < KTOP) sel[g * KTOP + rank] = i;
}

// ---------- Pooled-tensor gather ----------
__global__ __launch_bounds__(256) void k_pool(const float* __restrict__ x1,
                                              const float* __restrict__ x2,
                                              const float* __restrict__ x3,
                                              const float* __restrict__ x4,
                                              const int* __restrict__ sel,
                                              float* __restrict__ P) {
    int idx = blockIdx.x * 256 + threadIdx.x;
    if (idx >= PELEM) return;
    int g = idx / (KTOP * 97);
    int r = idx - g * (KTOP * 97);
    int p = r / 97;
    int f = r - p * 97;
    int v = sel[g * KTOP + p];
    float val = 0.f;
    if (v >= 0) {
        if (f < 32)      val = x1[v * 32 + f];
        else if (f < 64) val = x2[v * 32 + f - 32];
        else if (f < 96) val = x3[v * 32 + f - 64];
        else             val = x4[v];
    }
    P[idx] = val;
}

// ---------- CNN/MLP head: 256 threads, SIMPLE single-acc loops.
// Round-9 lesson: 4-way ILP + fc1 split => VGPR 132, occ 11%, 133 us. Keep
// per-thread register footprint small; win comes from 16 waves/CU vs 8. ----------
__global__ __launch_bounds__(256) void k_head(
    const float* __restrict__ Pg,
    const void* __restrict__ w5, const void* __restrict__ b5,
    const void* __restrict__ w6, const void* __restrict__ b6,
    const void* __restrict__ f1w, const void* __restrict__ f1b,
    const void* __restrict__ f2w, const void* __restrict__ f2b,
    const int* __restrict__ flagp, void* __restrict__ out) {
    __shared__ float P[KTOP * 97];
    __shared__ float W5[16 * 97];
    __shared__ float W6[32 * 16 * 5];
    __shared__ float H5[16][30];
    __shared__ float M[16][15];
    __shared__ float H6[352];
    __shared__ float Rp[256];
    __shared__ float R1[128];
    __shared__ float L[10];
    __shared__ float mls;
    int g = blockIdx.x;
    int tid = threadIdx.x;
    int bf = *flagp;

    for (int i = tid; i < KTOP * 97; i += 256) P[i] = Pg[g * (KTOP * 97) + i];
    if (bf) {   // vectorized bf16 weight staging
        const ushort4* w5v = (const ushort4*)w5;
        for (int i = tid; i < 388; i += 256) {           // 1552 = 388*4
            ushort4 h = w5v[i];
            int p = i * 4;
            W5[p] = u2f(h.x); W5[p + 1] = u2f(h.y); W5[p + 2] = u2f(h.z); W5[p + 3] = u2f(h.w);
        }
        const ushort4* w6v = (const ushort4*)w6;
        for (int i = tid; i < 640; i += 256) {           // 2560 = 640*4
            ushort4 h = w6v[i];
            int p = i * 4;
            W6[p] = u2f(h.x); W6[p + 1] = u2f(h.y); W6[p + 2] = u2f(h.z); W6[p + 3] = u2f(h.w);
        }
    } else {
        for (int i = tid; i < 16 * 97; i += 256) W5[i] = ((const float*)w5)[i];
        for (int i = tid; i < 2560; i += 256) W6[i] = ((const float*)w6)[i];
    }
    __syncthreads();
    for (int idx = tid; idx < 480; idx += 256) {   // conv5 + relu
        int o = idx / 30, p = idx - o * 30;
        float acc = LD(b5, o, bf);
        const float* pr = &P[p * 97];
        const float* wr = &W5[o * 97];
        for (int f = 0; f < 97; f++) acc += wr[f] * pr[f];
        H5[o][p] = fmaxf(acc, 0.f);
    }
    __syncthreads();
    for (int idx = tid; idx < 240; idx += 256) {   // maxpool2
        int o = idx / 15, q = idx - o * 15;
        M[o][q] = fmaxf(H5[o][2 * q], H5[o][2 * q + 1]);
    }
    __syncthreads();
    for (int idx = tid; idx < 352; idx += 256) {   // conv6 + relu
        int oc = idx / 11, tp = idx - oc * 11;
        float acc = LD(b6, oc, bf);
        const float* wr = &W6[oc * 80];
        for (int ic = 0; ic < 16; ic++) {
#pragma unroll
            for (int k = 0; k < 5; k++)
                acc += wr[ic * 5 + k] * M[ic][tp + k];
        }
        H6[idx] = fmaxf(acc, 0.f);
    }
    __syncthreads();
    {   // fc1: 2 threads per output column, 176 terms each, single accumulator
        int half = tid >> 7, col = tid & 127;
        int base = half * 176;
        float a = 0.f;
        for (int i = 0; i < 176; i++) {
            int ii = base + i;
            a += H6[ii] * LD(f1w, ii * 128 + col, bf);
        }
        Rp[tid] = a;
    }
    __syncthreads();
    if (tid < 128) R1[tid] = fmaxf(LD(f1b, tid, bf) + Rp[tid] + Rp[128 + tid], 0.f);
    __syncthreads();
    if (tid < 10) {   // fc2
        float acc = LD(f2b, tid, bf);
        for (int k = 0; k < 128; k++) acc += R1[k] * LD(f2w, k * 10 + tid, bf);
        L[tid] = acc;
    }
    __syncthreads();
    if (tid == 0) {
        float m = L[0];
        for (int c = 1; c < 10; c++) m = fmaxf(m, L[c]);
        float ssum = 0.f;
        for (int c = 0; c < 10; c++) ssum += expf(L[c] - m);
        mls = m + logf(ssum);
    }
    __syncthreads();
    if (tid < 10) {
        float v = L[tid] - mls;
        if (bf) ((bf16*)out)[g * 10 + tid] = __float2bfloat16(v);
        else    ((float*)out)[g * 10 + tid] = v;
    }
}

extern "C" void kernel_launch(void* const* d_in, const int* in_sizes, int n_in,
                              void* d_out, int out_size, void* d_ws, size_t ws_size,
                              hipStream_t stream) {
    const void* x   = d_in[0];
    const void* w1  = d_in[1];  const void* b1  = d_in[2];
    const void* w2  = d_in[3];  const void* b2  = d_in[4];
    const void* w3  = d_in[5];  const void* b3  = d_in[6];
    const void* w4  = d_in[7];  const void* b4  = d_in[8];
    const void* w5  = d_in[9];  const void* b5  = d_in[10];
    const void* w6  = d_in[11]; const void* b6  = d_in[12];
    const void* f1w = d_in[13]; const void* f1b = d_in[14];
    const void* f2w = d_in[15]; const void* f2b = d_in[16];
    const int* esrc  = (const int*)d_in[17];
    const int* edst  = (const int*)d_in[18];
    const int* batch = (const int*)d_in[19];

    char* w = (char*)d_ws;
    size_t off = 0;
    auto alloc = [&](size_t bytes) {
        void* p = w + off;
        off += (bytes + 255) & ~(size_t)255;
        return p;
    };
    int*   flag   = (int*)  alloc(256);
    int*   rs     = (int*)  alloc((size_t)N_NODES * 4);
    int*   re     = (int*)  alloc((size_t)N_NODES * 4);
    float* dis    = (float*)alloc((size_t)N_NODES * 4);
    int*   csr    = (int*)  alloc((size_t)NBKT * BKT_CAP * 4);
    float* t      = (float*)alloc((size_t)N_NODES * 32 * 4);   // aliased by ebuf (1st part)
    float* x1     = (float*)alloc((size_t)N_NODES * 32 * 4);   // aliased by ebuf (2nd part)
    float* x2     = (float*)alloc((size_t)N_NODES * 32 * 4);
    float* x3     = (float*)alloc((size_t)N_NODES * 32 * 4);
    float* x4     = (float*)alloc((size_t)N_NODES * 4);
    int*   gstart = (int*)  alloc((size_t)(NGRAPH + 1) * 4);
    int*   sel    = (int*)  alloc((size_t)NGRAPH * KTOP * 4);
    float* Pg     = (float*)alloc((size_t)PELEM * 4);
    int*   cur    = (int*)  alloc((size_t)NBKT * 4);
    (void)ws_size; (void)n_in; (void)in_sizes; (void)out_size;

    // ebuf (padded bucketed packed edges, 14.8 MB) aliases t + head of x1,
    // both of which are dead until k_mm1.
    int* ebuf = (int*)t;

    hipMemsetAsync(sel, 0xFF, (size_t)NGRAPH * KTOP * 4, stream);

    int nb   = (N_NODES + 255) / 256;
    int mb32 = N_NODES / 32;
    int ab   = N_NODES / 4;
    int a1b  = N_NODES / 16;
    int pb   = (PELEM + 255) / 256;

    k_detect<<<1, 64, 0, stream>>>(w1, flag);
    k_icur<<<(NBKT + 255) / 256, 256, 0, stream>>>(cur);
    k_scat<<<NTILE, 256, 0, stream>>>(esrc, edst, cur, ebuf);
    k_bcsr<<<NBKT, 256, 0, stream>>>(ebuf, cur, rs, re, dis, csr);
    k_gstart<<<5, 256, 0, stream>>>(batch, gstart);

    k_mm1<<<mb32, 256, 0, stream>>>(x, w1, flag, dis, t);
    k_agg32<<<ab, 256, 0, stream>>>((const float4*)t, rs, re, csr, dis, b1, flag, (float4*)x1);
    k_mm32<<<mb32, 256, 0, stream>>>(x1, w2, flag, dis, t);
    k_agg32<<<ab, 256, 0, stream>>>((const float4*)t, rs, re, csr, dis, b2, flag, (float4*)x2);
    k_mm32<<<mb32, 256, 0, stream>>>(x2, w3, flag, dis, t);
    k_agg32<<<ab, 256, 0, stream>>>((const float4*)t, rs, re, csr, dis, b3, flag, (float4*)x3);
    k_mm_out1<<<(N_NODES + 7) / 8, 256, 0, stream>>>(x3, w4, flag, dis, t);
    k_agg1<<<a1b, 256, 0, stream>>>(t, rs, re, csr, dis, b4, flag, x4);
    k_rank<<<nb, 256, 0, stream>>>(batch, gstart, x4, sel);
    k_pool<<<pb, 256, 0, stream>>>(x1, x2, x3, x4, sel, Pg);
    k_head<<<NGRAPH, 256, 0, stream>>>(Pg, w5, b5, w6, b6,
                                       f1w, f1b, f2w, f2b, flag, (void*)d_out);
}

// Round 3
// 597.708 us; speedup vs baseline: 1.0464x; 1.0464x over previous
//
#include <hip/hip_runtime.h>
#include <hip/hip_bf16.h>

#define N_NODES 100000
#define N_EDGES 3200000
#define NGRAPH 1024
#define KTOP 30
#define PELEM (NGRAPH * KTOP * 97)         // pooled tensor elements

#define NBKT 782                            // ceil(100000 / 128) node buckets
#define NTILE 391                           // edge tiles
#define TILE 8192                           // edges per tile (391*8192 >= 3.2M)
#define BKT_CAP 4736                        // padded bucket capacity (mean 4096 + 10 sigma)

typedef __hip_bfloat16 bf16;
typedef float vfloat4 __attribute__((ext_vector_type(4)));   // native vec for nt-store

__device__ __forceinline__ float u2f(unsigned short h) {
    return __uint_as_float(((unsigned int)h) << 16);
}
// Flag-steered scalar load of a float-tensor input that may be bf16 or f32.
__device__ __forceinline__ float LD(const void* p, int i, int bf) {
    if (bf) return u2f(((const unsigned short*)p)[i]);
    return ((const float*)p)[i];
}

// ---------- dtype probe ----------
__global__ void k_detect(const void* w1, int* flag) {
    if (threadIdx.x == 0 && blockIdx.x == 0) {
        const unsigned short* u = (const unsigned short*)w1;
        int plausible = 0;
        for (int i = 0; i < 64; i++) {
            float a = fabsf(u2f(u[2 * i]));
            if (a == 0.f || (a >= 9.765625e-4f && a <= 2.0f)) plausible++;
        }
        *flag = (plausible >= 40) ? 1 : 0;
    }
}

// ---------- one-pass padded-bucket edge partition ----------
// cur[b] pre-init to b*BKT_CAP; tiles reserve contiguous ranges per bucket
// via one global atomicAdd per (tile,bucket). Records packed 24-bit:
// (dst&127)<<17 | src. Bucket padding is never read downstream (rs/re).
__global__ void k_icur(int* __restrict__ cur) {
    int i = blockIdx.x * 256 + threadIdx.x;
    if (i < NBKT) cur[i] = i * BKT_CAP;
}

__global__ __launch_bounds__(256) void k_scat(const int* __restrict__ src,
                                              const int* __restrict__ dst,
                                              int* __restrict__ cur,
                                              int* __restrict__ ebuf) {
    __shared__ int pk[TILE];                 // 32 KB packed records
    __shared__ unsigned short bk[TILE];      // 16 KB bucket ids (0xFFFF = skip)
    __shared__ int h[NBKT];                  // per-tile histogram, then cursor
    __shared__ int base[NBKT];               // reserved global base per bucket
    int tid = threadIdx.x;
    int ebase = blockIdx.x * TILE;
    for (int i = tid; i < NBKT; i += 256) h[i] = 0;
    __syncthreads();
    for (int i = tid; i < TILE; i += 256) {
        int e = ebase + i;
        int bkt = 0xFFFF;
        if (e < N_EDGES) {
            int s = __builtin_nontemporal_load(src + e);
            int d = __builtin_nontemporal_load(dst + e);
            if (s != d) {
                bkt = d >> 7;
                pk[i] = ((d & 127) << 17) | s;
                atomicAdd(&h[bkt], 1);
            }
        }
        bk[i] = (unsigned short)bkt;
    }
    __syncthreads();
    for (int i = tid; i < NBKT; i += 256) {
        int c = h[i];
        base[i] = c ? atomicAdd(&cur[i], c) : 0;
    }
    __syncthreads();
    for (int i = tid; i < NBKT; i += 256) h[i] = 0;   // reuse as local cursors
    __syncthreads();
    for (int i = tid; i < TILE; i += 256) {
        int bkt = bk[i];
        if (bkt != 0xFFFF) {
            int p = base[bkt] + atomicAdd(&h[bkt], 1);
            if (p < (bkt + 1) * BKT_CAP) ebuf[p] = pk[i];   // overflow guard (never fires)
        }
    }
}

__global__ __launch_bounds__(256) void k_bcsr(const int* __restrict__ ebuf,
                                              const int* __restrict__ cur,
                                              int* __restrict__ rs,
                                              int* __restrict__ re,
                                              float* __restrict__ dis,
                                              int* __restrict__ csr) {
    __shared__ int dloc[128];
    __shared__ int sc[128];
    int b = blockIdx.x;
    int node0 = b << 7;
    int nn = N_NODES - node0; if (nn > 128) nn = 128;
    int tid = threadIdx.x;
    if (tid < 128) dloc[tid] = 0;
    __syncthreads();
    int s = b * BKT_CAP;
    int cnt = cur[b] - s; if (cnt > BKT_CAP) cnt = BKT_CAP;
    int e = s + cnt;
    for (int i = s + tid; i < e; i += 256)
        atomicAdd(&dloc[ebuf[i] >> 17], 1);
    __syncthreads();
    if (tid < 128) sc[tid] = dloc[tid];
    __syncthreads();
    for (int off = 1; off < 128; off <<= 1) {
        int t = (tid >= off && tid < 128) ? sc[tid - off] : 0;
        __syncthreads();
        if (tid < 128) sc[tid] += t;
        __syncthreads();
    }
    if (tid < nn) {
        int st = s + sc[tid] - dloc[tid];
        rs[node0 + tid] = st;
        re[node0 + tid] = st + dloc[tid];
        dis[node0 + tid] = rsqrtf((float)dloc[tid] + 1.0f);
    }
    __syncthreads();
    if (tid < 128) dloc[tid] = s + sc[tid] - dloc[tid];  // cursors
    __syncthreads();
    for (int i = s + tid; i < e; i += 256) {
        int pv = ebuf[i];
        int pos = atomicAdd(&dloc[pv >> 17], 1);
        csr[pos] = pv & 0x1FFFF;
    }
}

__global__ void k_gstart(const int* __restrict__ batch, int* __restrict__ gstart) {
    int g = blockIdx.x * 256 + threadIdx.x;
    if (g > NGRAPH) return;
    int lo = 0, hi = N_NODES;
    while (lo < hi) {
        int mid = (lo + hi) >> 1;
        if (batch[mid] < g) lo = mid + 1; else hi = mid;
    }
    gstart[g] = lo;
}

// ---------- GCN layers (activations f32; ts = dis * (x @ W)) ----------
__global__ __launch_bounds__(256) void k_mm1(const void* __restrict__ x,
                                             const void* __restrict__ w,
                                             const int* __restrict__ flagp,
                                             const float* __restrict__ dis,
                                             float* __restrict__ ts) {
    __shared__ float Wl[128 * 32];
    __shared__ float Xs[32][128];
    int bf = *flagp;
    int tid = threadIdx.x;
    int nbase = blockIdx.x * 32;          // N_NODES % 32 == 0: always full
    if (bf) {
        const ushort4* wv = (const ushort4*)w;
        for (int idx = tid; idx < 1024; idx += 256) {
            ushort4 h = wv[idx];
            int p = idx * 4;
            Wl[p] = u2f(h.x); Wl[p + 1] = u2f(h.y); Wl[p + 2] = u2f(h.z); Wl[p + 3] = u2f(h.w);
        }
        const ushort4* xv = (const ushort4*)x;
        for (int idx = tid; idx < 1024; idx += 256) {
            int nd = idx >> 5, q = idx & 31;
            ushort4 h = xv[(size_t)(nbase + nd) * 32 + q];
            float* d = &Xs[nd][q * 4];
            d[0] = u2f(h.x); d[1] = u2f(h.y); d[2] = u2f(h.z); d[3] = u2f(h.w);
        }
    } else {
        const float* wf = (const float*)w;
        for (int idx = tid; idx < 4096; idx += 256) Wl[idx] = wf[idx];
        const float* xf = (const float*)x;
        for (int idx = tid; idx < 4096; idx += 256)
            Xs[idx >> 7][idx & 127] = xf[(size_t)nbase * 128 + idx];
    }
    __syncthreads();
    int grp = tid >> 5, col = tid & 31;
    for (int rep = 0; rep < 4; rep++) {
        int sub = grp + 8 * rep;
        int node = nbase + sub;
        float acc = 0.f;
#pragma unroll 8
        for (int k = 0; k < 128; k++) acc += Xs[sub][k] * Wl[k * 32 + col];
        ts[node * 32 + col] = dis[node] * acc;
    }
}

__global__ __launch_bounds__(256) void k_mm32(const float* __restrict__ xin,
                                              const void* __restrict__ w,
                                              const int* __restrict__ flagp,
                                              const float* __restrict__ dis,
                                              float* __restrict__ ts) {
    __shared__ float Wl[32 * 32];
    __shared__ float Xs[32][32];
    int bf = *flagp;
    int tid = threadIdx.x;
    int nbase = blockIdx.x * 32;
    if (bf) {
        const ushort4* wv = (const ushort4*)w;
        for (int idx = tid; idx < 256; idx += 256) {
            ushort4 h = wv[idx];
            int p = idx * 4;
            Wl[p] = u2f(h.x); Wl[p + 1] = u2f(h.y); Wl[p + 2] = u2f(h.z); Wl[p + 3] = u2f(h.w);
        }
    } else {
        const float* wf = (const float*)w;
        for (int idx = tid; idx < 1024; idx += 256) Wl[idx] = wf[idx];
    }
    {
        const float4* xv = (const float4*)xin;
        int nd = tid >> 3, q = tid & 7;
        float4 v = xv[(size_t)(nbase + nd) * 8 + q];
        float* d = &Xs[nd][q * 4];
        d[0] = v.x; d[1] = v.y; d[2] = v.z; d[3] = v.w;
    }
    __syncthreads();
    int grp = tid >> 5, col = tid & 31;
    for (int rep = 0; rep < 4; rep++) {
        int sub = grp + 8 * rep;
        int node = nbase + sub;
        float acc = 0.f;
#pragma unroll
        for (int k = 0; k < 32; k++) acc += Xs[sub][k] * Wl[k * 32 + col];
        ts[node * 32 + col] = dis[node] * acc;
    }
}

__global__ __launch_bounds__(256) void k_mm_out1(const float* __restrict__ xin,
                                                 const void* __restrict__ w4,
                                                 const int* __restrict__ flagp,
                                                 const float* __restrict__ dis,
                                                 float* __restrict__ ts4) {
    int node = blockIdx.x * 8 + (threadIdx.x >> 5);
    int lane = threadIdx.x & 31;
    if (node >= N_NODES) return;
    int bf = *flagp;
    float v = xin[node * 32 + lane] * LD(w4, lane, bf);
    for (int off = 16; off; off >>= 1) v += __shfl_down(v, off, 32);
    if (lane == 0) ts4[node] = dis[node] * v;
}

// One wave64 per node; 8 lanes per row (float4/lane); gather loop unrolled x4
// => up to 32 neighbor rows in flight per wave. csr/ts reads are CACHED
// (round-1 lesson: nt loads refetch shared lines, +14% time). Output rows
// use nontemporal stores (native ext-vector type) so the 12.5 MB write
// stream does not write-allocate in L2 and evict ts lines.
__global__ __launch_bounds__(256) void k_agg32(const float4* __restrict__ ts,
                                               const int* __restrict__ rs,
                                               const int* __restrict__ re,
                                               const int* __restrict__ csr,
                                               const float* __restrict__ dis,
                                               const void* __restrict__ b,
                                               const int* __restrict__ flagp,
                                               float4* __restrict__ out) {
    int node = blockIdx.x * 4 + (threadIdx.x >> 6);
    int lane = threadIdx.x & 63;
    int q   = lane & 7;
    int grp = lane >> 3;
    int bf = *flagp;
    int s = rs[node], e = re[node];
    float4 a0 = make_float4(0.f, 0.f, 0.f, 0.f);
    float4 a1 = a0, a2 = a0, a3 = a0;
    int i = s + grp;
    for (; i + 24 < e; i += 32) {
        int v0 = csr[i], v1 = csr[i + 8], v2 = csr[i + 16], v3 = csr[i + 24];
        float4 m0 = ts[v0 * 8 + q];
        float4 m1 = ts[v1 * 8 + q];
        float4 m2 = ts[v2 * 8 + q];
        float4 m3 = ts[v3 * 8 + q];
        a0.x += m0.x; a0.y += m0.y; a0.z += m0.z; a0.w += m0.w;
        a1.x += m1.x; a1.y += m1.y; a1.z += m1.z; a1.w += m1.w;
        a2.x += m2.x; a2.y += m2.y; a2.z += m2.z; a2.w += m2.w;
        a3.x += m3.x; a3.y += m3.y; a3.z += m3.z; a3.w += m3.w;
    }
    for (; i < e; i += 8) {
        float4 m = ts[csr[i] * 8 + q];
        a0.x += m.x; a0.y += m.y; a0.z += m.z; a0.w += m.w;
    }
    float4 acc;
    acc.x = (a0.x + a1.x) + (a2.x + a3.x);
    acc.y = (a0.y + a1.y) + (a2.y + a3.y);
    acc.z = (a0.z + a1.z) + (a2.z + a3.z);
    acc.w = (a0.w + a1.w) + (a2.w + a3.w);
#pragma unroll
    for (int off = 8; off < 64; off <<= 1) {
        acc.x += __shfl_xor(acc.x, off);
        acc.y += __shfl_xor(acc.y, off);
        acc.z += __shfl_xor(acc.z, off);
        acc.w += __shfl_xor(acc.w, off);
    }
    if (grp == 0) {
        float4 self = ts[node * 8 + q];
        float d = dis[node];
        vfloat4 r;
        r.x = tanhf(d * (acc.x + self.x) + LD(b, q * 4 + 0, bf));
        r.y = tanhf(d * (acc.y + self.y) + LD(b, q * 4 + 1, bf));
        r.z = tanhf(d * (acc.z + self.z) + LD(b, q * 4 + 2, bf));
        r.w = tanhf(d * (acc.w + self.w) + LD(b, q * 4 + 3, bf));
        __builtin_nontemporal_store(r, (vfloat4*)&out[node * 8 + q]);
    }
}

// 16 lanes per node.
__global__ __launch_bounds__(256) void k_agg1(const float* __restrict__ ts4,
                                              const int* __restrict__ rs,
                                              const int* __restrict__ re,
                                              const int* __restrict__ csr,
                                              const float* __restrict__ dis,
                                              const void* __restrict__ b4,
                                              const int* __restrict__ flagp,
                                              float* __restrict__ x4) {
    int node = blockIdx.x * 16 + (threadIdx.x >> 4);
    int lane = threadIdx.x & 15;
    int s = rs[node], e = re[node];
    float acc = 0.f;
    for (int i = s + lane; i < e; i += 16) acc += ts4[csr[i]];
#pragma unroll
    for (int off = 1; off < 16; off <<= 1) acc += __shfl_xor(acc, off);
    if (lane == 0) {
        int bf = *flagp;
        x4[node] = tanhf(dis[node] * (acc + ts4[node]) + LD(b4, 0, bf));
    }
}

// ---------- SortPooling rank ----------
__global__ __launch_bounds__(256) void k_rank(const int* __restrict__ batch,
                                              const int* __restrict__ gstart,
                                              const float* __restrict__ x4,
                                              int* __restrict__ sel) {
    int i = blockIdx.x * 256 + threadIdx.x;
    if (i >= N_NODES) return;
    int g = batch[i];
    int s = gstart[g], e = gstart[g + 1];
    float ki = x4[i];
    int rank = 0;
    for (int j = s; j < e; j++) {
        float kj = x4[j];
        rank += (kj > ki) || (kj == ki && j < i);
    }
    if (rank < KTOP) sel[g * KTOP + rank] = i;
}

// ---------- Pooled-tensor gather ----------
__global__ __launch_bounds__(256) void k_pool(const float* __restrict__ x1,
                                              const float* __restrict__ x2,
                                              const float* __restrict__ x3,
                                              const float* __restrict__ x4,
                                              const int* __restrict__ sel,
                                              float* __restrict__ P) {
    int idx = blockIdx.x * 256 + threadIdx.x;
    if (idx >= PELEM) return;
    int g = idx / (KTOP * 97);
    int r = idx - g * (KTOP * 97);
    int p = r / 97;
    int f = r - p * 97;
    int v = sel[g * KTOP + p];
    float val = 0.f;
    if (v >= 0) {
        if (f < 32)      val = x1[v * 32 + f];
        else if (f < 64) val = x2[v * 32 + f - 32];
        else if (f < 96) val = x3[v * 32 + f - 64];
        else             val = x4[v];
    }
    P[idx] = val;
}

// ---------- CNN/MLP head: 256 threads, SIMPLE single-acc loops.
// Round-9 lesson: 4-way ILP + fc1 split => VGPR 132, occ 11%, 133 us. Keep
// per-thread register footprint small; win comes from 16 waves/CU vs 8. ----------
__global__ __launch_bounds__(256) void k_head(
    const float* __restrict__ Pg,
    const void* __restrict__ w5, const void* __restrict__ b5,
    const void* __restrict__ w6, const void* __restrict__ b6,
    const void* __restrict__ f1w, const void* __restrict__ f1b,
    const void* __restrict__ f2w, const void* __restrict__ f2b,
    const int* __restrict__ flagp, void* __restrict__ out) {
    __shared__ float P[KTOP * 97];
    __shared__ float W5[16 * 97];
    __shared__ float W6[32 * 16 * 5];
    __shared__ float H5[16][30];
    __shared__ float M[16][15];
    __shared__ float H6[352];
    __shared__ float Rp[256];
    __shared__ float R1[128];
    __shared__ float L[10];
    __shared__ float mls;
    int g = blockIdx.x;
    int tid = threadIdx.x;
    int bf = *flagp;

    for (int i = tid; i < KTOP * 97; i += 256) P[i] = Pg[g * (KTOP * 97) + i];
    if (bf) {   // vectorized bf16 weight staging
        const ushort4* w5v = (const ushort4*)w5;
        for (int i = tid; i < 388; i += 256) {           // 1552 = 388*4
            ushort4 h = w5v[i];
            int p = i * 4;
            W5[p] = u2f(h.x); W5[p + 1] = u2f(h.y); W5[p + 2] = u2f(h.z); W5[p + 3] = u2f(h.w);
        }
        const ushort4* w6v = (const ushort4*)w6;
        for (int i = tid; i < 640; i += 256) {           // 2560 = 640*4
            ushort4 h = w6v[i];
            int p = i * 4;
            W6[p] = u2f(h.x); W6[p + 1] = u2f(h.y); W6[p + 2] = u2f(h.z); W6[p + 3] = u2f(h.w);
        }
    } else {
        for (int i = tid; i < 16 * 97; i += 256) W5[i] = ((const float*)w5)[i];
        for (int i = tid; i < 2560; i += 256) W6[i] = ((const float*)w6)[i];
    }
    __syncthreads();
    for (int idx = tid; idx < 480; idx += 256) {   // conv5 + relu
        int o = idx / 30, p = idx - o * 30;
        float acc = LD(b5, o, bf);
        const float* pr = &P[p * 97];
        const float* wr = &W5[o * 97];
        for (int f = 0; f < 97; f++) acc += wr[f] * pr[f];
        H5[o][p] = fmaxf(acc, 0.f);
    }
    __syncthreads();
    for (int idx = tid; idx < 240; idx += 256) {   // maxpool2
        int o = idx / 15, q = idx - o * 15;
        M[o][q] = fmaxf(H5[o][2 * q], H5[o][2 * q + 1]);
    }
    __syncthreads();
    for (int idx = tid; idx < 352; idx += 256) {   // conv6 + relu
        int oc = idx / 11, tp = idx - oc * 11;
        float acc = LD(b6, oc, bf);
        const float* wr = &W6[oc * 80];
        for (int ic = 0; ic < 16; ic++) {
#pragma unroll
            for (int k = 0; k < 5; k++)
                acc += wr[ic * 5 + k] * M[ic][tp + k];
        }
        H6[idx] = fmaxf(acc, 0.f);
    }
    __syncthreads();
    {   // fc1: 2 threads per output column, 176 terms each, single accumulator
        int half = tid >> 7, col = tid & 127;
        int base = half * 176;
        float a = 0.f;
        for (int i = 0; i < 176; i++) {
            int ii = base + i;
            a += H6[ii] * LD(f1w, ii * 128 + col, bf);
        }
        Rp[tid] = a;
    }
    __syncthreads();
    if (tid < 128) R1[tid] = fmaxf(LD(f1b, tid, bf) + Rp[tid] + Rp[128 + tid], 0.f);
    __syncthreads();
    if (tid < 10) {   // fc2
        float acc = LD(f2b, tid, bf);
        for (int k = 0; k < 128; k++) acc += R1[k] * LD(f2w, k * 10 + tid, bf);
        L[tid] = acc;
    }
    __syncthreads();
    if (tid == 0) {
        float m = L[0];
        for (int c = 1; c < 10; c++) m = fmaxf(m, L[c]);
        float ssum = 0.f;
        for (int c = 0; c < 10; c++) ssum += expf(L[c] - m);
        mls = m + logf(ssum);
    }
    __syncthreads();
    if (tid < 10) {
        float v = L[tid] - mls;
        if (bf) ((bf16*)out)[g * 10 + tid] = __float2bfloat16(v);
        else    ((float*)out)[g * 10 + tid] = v;
    }
}

extern "C" void kernel_launch(void* const* d_in, const int* in_sizes, int n_in,
                              void* d_out, int out_size, void* d_ws, size_t ws_size,
                              hipStream_t stream) {
    const void* x   = d_in[0];
    const void* w1  = d_in[1];  const void* b1  = d_in[2];
    const void* w2  = d_in[3];  const void* b2  = d_in[4];
    const void* w3  = d_in[5];  const void* b3  = d_in[6];
    const void* w4  = d_in[7];  const void* b4  = d_in[8];
    const void* w5  = d_in[9];  const void* b5  = d_in[10];
    const void* w6  = d_in[11]; const void* b6  = d_in[12];
    const void* f1w = d_in[13]; const void* f1b = d_in[14];
    const void* f2w = d_in[15]; const void* f2b = d_in[16];
    const int* esrc  = (const int*)d_in[17];
    const int* edst  = (const int*)d_in[18];
    const int* batch = (const int*)d_in[19];

    char* w = (char*)d_ws;
    size_t off = 0;
    auto alloc = [&](size_t bytes) {
        void* p = w + off;
        off += (bytes + 255) & ~(size_t)255;
        return p;
    };
    int*   flag   = (int*)  alloc(256);
    int*   rs     = (int*)  alloc((size_t)N_NODES * 4);
    int*   re     = (int*)  alloc((size_t)N_NODES * 4);
    float* dis    = (float*)alloc((size_t)N_NODES * 4);
    int*   csr    = (int*)  alloc((size_t)NBKT * BKT_CAP * 4);
    float* t      = (float*)alloc((size_t)N_NODES * 32 * 4);   // aliased by ebuf (1st part)
    float* x1     = (float*)alloc((size_t)N_NODES * 32 * 4);   // aliased by ebuf (2nd part)
    float* x2     = (float*)alloc((size_t)N_NODES * 32 * 4);
    float* x3     = (float*)alloc((size_t)N_NODES * 32 * 4);
    float* x4     = (float*)alloc((size_t)N_NODES * 4);
    int*   gstart = (int*)  alloc((size_t)(NGRAPH + 1) * 4);
    int*   sel    = (int*)  alloc((size_t)NGRAPH * KTOP * 4);
    float* Pg     = (float*)alloc((size_t)PELEM * 4);
    int*   cur    = (int*)  alloc((size_t)NBKT * 4);
    (void)ws_size; (void)n_in; (void)in_sizes; (void)out_size;

    // ebuf (padded bucketed packed edges, 14.8 MB) aliases t + head of x1,
    // both of which are dead until k_mm1.
    int* ebuf = (int*)t;

    (void)hipMemsetAsync(sel, 0xFF, (size_t)NGRAPH * KTOP * 4, stream);

    int nb   = (N_NODES + 255) / 256;
    int mb32 = N_NODES / 32;
    int ab   = N_NODES / 4;
    int a1b  = N_NODES / 16;
    int pb   = (PELEM + 255) / 256;

    k_detect<<<1, 64, 0, stream>>>(w1, flag);
    k_icur<<<(NBKT + 255) / 256, 256, 0, stream>>>(cur);
    k_scat<<<NTILE, 256, 0, stream>>>(esrc, edst, cur, ebuf);
    k_bcsr<<<NBKT, 256, 0, stream>>>(ebuf, cur, rs, re, dis, csr);
    k_gstart<<<5, 256, 0, stream>>>(batch, gstart);

    k_mm1<<<mb32, 256, 0, stream>>>(x, w1, flag, dis, t);
    k_agg32<<<ab, 256, 0, stream>>>((const float4*)t, rs, re, csr, dis, b1, flag, (float4*)x1);
    k_mm32<<<mb32, 256, 0, stream>>>(x1, w2, flag, dis, t);
    k_agg32<<<ab, 256, 0, stream>>>((const float4*)t, rs, re, csr, dis, b2, flag, (float4*)x2);
    k_mm32<<<mb32, 256, 0, stream>>>(x2, w3, flag, dis, t);
    k_agg32<<<ab, 256, 0, stream>>>((const float4*)t, rs, re, csr, dis, b3, flag, (float4*)x3);
    k_mm_out1<<<(N_NODES + 7) / 8, 256, 0, stream>>>(x3, w4, flag, dis, t);
    k_agg1<<<a1b, 256, 0, stream>>>(t, rs, re, csr, dis, b4, flag, x4);
    k_rank<<<nb, 256, 0, stream>>>(batch, gstart, x4, sel);
    k_pool<<<pb, 256, 0, stream>>>(x1, x2, x3, x4, sel, Pg);
    k_head<<<NGRAPH, 256, 0, stream>>>(Pg, w5, b5, w6, b6,
                                       f1w, f1b, f2w, f2b, flag, (void*)d_out);
}

// Round 4
// 587.211 us; speedup vs baseline: 1.0651x; 1.0179x over previous
//
#include <hip/hip_runtime.h>
#include <hip/hip_bf16.h>

#define N_NODES 100000
#define N_EDGES 3200000
#define NGRAPH 1024
#define KTOP 30
#define PELEM (NGRAPH * KTOP * 97)         // pooled tensor elements

#define NBKT 782                            // ceil(100000 / 128) node buckets
#define NTILE 391                           // edge tiles
#define TILE 8192                           // edges per tile (391*8192 >= 3.2M)
#define BKT_CAP 4736                        // padded bucket capacity (mean 4096 + 10 sigma)

typedef __hip_bfloat16 bf16;
typedef float vfloat4 __attribute__((ext_vector_type(4)));   // native vec for nt-store

__device__ __forceinline__ float u2f(unsigned short h) {
    return __uint_as_float(((unsigned int)h) << 16);
}
// Flag-steered scalar load of a float-tensor input that may be bf16 or f32.
__device__ __forceinline__ float LD(const void* p, int i, int bf) {
    if (bf) return u2f(((const unsigned short*)p)[i]);
    return ((const float*)p)[i];
}

// ---------- dtype probe ----------
__global__ void k_detect(const void* w1, int* flag) {
    if (threadIdx.x == 0 && blockIdx.x == 0) {
        const unsigned short* u = (const unsigned short*)w1;
        int plausible = 0;
        for (int i = 0; i < 64; i++) {
            float a = fabsf(u2f(u[2 * i]));
            if (a == 0.f || (a >= 9.765625e-4f && a <= 2.0f)) plausible++;
        }
        *flag = (plausible >= 40) ? 1 : 0;
    }
}

// ---------- one-pass padded-bucket edge partition ----------
// cur[b] pre-init to b*BKT_CAP; tiles reserve contiguous ranges per bucket
// via one global atomicAdd per (tile,bucket). Records packed 24-bit:
// (dst&127)<<17 | src. Bucket padding is never read downstream (rs/re).
__global__ void k_icur(int* __restrict__ cur) {
    int i = blockIdx.x * 256 + threadIdx.x;
    if (i < NBKT) cur[i] = i * BKT_CAP;
}

__global__ __launch_bounds__(256) void k_scat(const int* __restrict__ src,
                                              const int* __restrict__ dst,
                                              int* __restrict__ cur,
                                              int* __restrict__ ebuf) {
    __shared__ int pk[TILE];                 // 32 KB packed records
    __shared__ unsigned short bk[TILE];      // 16 KB bucket ids (0xFFFF = skip)
    __shared__ int h[NBKT];                  // per-tile histogram, then cursor
    __shared__ int base[NBKT];               // reserved global base per bucket
    int tid = threadIdx.x;
    int ebase = blockIdx.x * TILE;
    for (int i = tid; i < NBKT; i += 256) h[i] = 0;
    __syncthreads();
    for (int i = tid; i < TILE; i += 256) {
        int e = ebase + i;
        int bkt = 0xFFFF;
        if (e < N_EDGES) {
            int s = __builtin_nontemporal_load(src + e);
            int d = __builtin_nontemporal_load(dst + e);
            if (s != d) {
                bkt = d >> 7;
                pk[i] = ((d & 127) << 17) | s;
                atomicAdd(&h[bkt], 1);
            }
        }
        bk[i] = (unsigned short)bkt;
    }
    __syncthreads();
    for (int i = tid; i < NBKT; i += 256) {
        int c = h[i];
        base[i] = c ? atomicAdd(&cur[i], c) : 0;
    }
    __syncthreads();
    for (int i = tid; i < NBKT; i += 256) h[i] = 0;   // reuse as local cursors
    __syncthreads();
    for (int i = tid; i < TILE; i += 256) {
        int bkt = bk[i];
        if (bkt != 0xFFFF) {
            int p = base[bkt] + atomicAdd(&h[bkt], 1);
            if (p < (bkt + 1) * BKT_CAP) ebuf[p] = pk[i];   // overflow guard (never fires)
        }
    }
}

__global__ __launch_bounds__(256) void k_bcsr(const int* __restrict__ ebuf,
                                              const int* __restrict__ cur,
                                              int* __restrict__ rs,
                                              int* __restrict__ re,
                                              float* __restrict__ dis,
                                              int* __restrict__ csr) {
    __shared__ int dloc[128];
    __shared__ int sc[128];
    int b = blockIdx.x;
    int node0 = b << 7;
    int nn = N_NODES - node0; if (nn > 128) nn = 128;
    int tid = threadIdx.x;
    if (tid < 128) dloc[tid] = 0;
    __syncthreads();
    int s = b * BKT_CAP;
    int cnt = cur[b] - s; if (cnt > BKT_CAP) cnt = BKT_CAP;
    int e = s + cnt;
    for (int i = s + tid; i < e; i += 256)
        atomicAdd(&dloc[ebuf[i] >> 17], 1);
    __syncthreads();
    if (tid < 128) sc[tid] = dloc[tid];
    __syncthreads();
    for (int off = 1; off < 128; off <<= 1) {
        int t = (tid >= off && tid < 128) ? sc[tid - off] : 0;
        __syncthreads();
        if (tid < 128) sc[tid] += t;
        __syncthreads();
    }
    if (tid < nn) {
        int st = s + sc[tid] - dloc[tid];
        rs[node0 + tid] = st;
        re[node0 + tid] = st + dloc[tid];
        dis[node0 + tid] = rsqrtf((float)dloc[tid] + 1.0f);
    }
    __syncthreads();
    if (tid < 128) dloc[tid] = s + sc[tid] - dloc[tid];  // cursors
    __syncthreads();
    for (int i = s + tid; i < e; i += 256) {
        int pv = ebuf[i];
        int pos = atomicAdd(&dloc[pv >> 17], 1);
        csr[pos] = pv & 0x1FFFF;
    }
}

__global__ void k_gstart(const int* __restrict__ batch, int* __restrict__ gstart) {
    int g = blockIdx.x * 256 + threadIdx.x;
    if (g > NGRAPH) return;
    int lo = 0, hi = N_NODES;
    while (lo < hi) {
        int mid = (lo + hi) >> 1;
        if (batch[mid] < g) lo = mid + 1; else hi = mid;
    }
    gstart[g] = lo;
}

// ---------- GCN layer 1 matmul (activations f32; ts = dis * (x @ W)) ----------
__global__ __launch_bounds__(256) void k_mm1(const void* __restrict__ x,
                                             const void* __restrict__ w,
                                             const int* __restrict__ flagp,
                                             const float* __restrict__ dis,
                                             float* __restrict__ ts) {
    __shared__ float Wl[128 * 32];
    __shared__ float Xs[32][128];
    int bf = *flagp;
    int tid = threadIdx.x;
    int nbase = blockIdx.x * 32;          // N_NODES % 32 == 0: always full
    if (bf) {
        const ushort4* wv = (const ushort4*)w;
        for (int idx = tid; idx < 1024; idx += 256) {
            ushort4 h = wv[idx];
            int p = idx * 4;
            Wl[p] = u2f(h.x); Wl[p + 1] = u2f(h.y); Wl[p + 2] = u2f(h.z); Wl[p + 3] = u2f(h.w);
        }
        const ushort4* xv = (const ushort4*)x;
        for (int idx = tid; idx < 1024; idx += 256) {
            int nd = idx >> 5, q = idx & 31;
            ushort4 h = xv[(size_t)(nbase + nd) * 32 + q];
            float* d = &Xs[nd][q * 4];
            d[0] = u2f(h.x); d[1] = u2f(h.y); d[2] = u2f(h.z); d[3] = u2f(h.w);
        }
    } else {
        const float* wf = (const float*)w;
        for (int idx = tid; idx < 4096; idx += 256) Wl[idx] = wf[idx];
        const float* xf = (const float*)x;
        for (int idx = tid; idx < 4096; idx += 256)
            Xs[idx >> 7][idx & 127] = xf[(size_t)nbase * 128 + idx];
    }
    __syncthreads();
    int grp = tid >> 5, col = tid & 31;
    for (int rep = 0; rep < 4; rep++) {
        int sub = grp + 8 * rep;
        int node = nbase + sub;
        float acc = 0.f;
#pragma unroll 8
        for (int k = 0; k < 128; k++) acc += Xs[sub][k] * Wl[k * 32 + col];
        ts[node * 32 + col] = dis[node] * acc;
    }
}

// ---------- Fused aggregate + next-layer matmul ----------
// One wave64 per node; 8 lanes per row (float4/lane); gather loop unrolled x4
// => up to 32 neighbor rows in flight per wave. csr/ts reads CACHED (round-1
// lesson: nt loads refetch shared lines, +14%). Epilogue: write x_out row
// (nt-store) AND stash it in LDS; then the block computes
// ts_next = dis * (x_out @ Wn) in-place, deleting the separate k_mm32 /
// k_mm_out1 kernels and their 12.8 MB x re-reads.
// OUTF = next-layer output width (32 for w2/w3, 1 for w4).
template<int OUTF>
__global__ __launch_bounds__(256) void k_aggf(const float4* __restrict__ ts,
                                              const int* __restrict__ rs,
                                              const int* __restrict__ re,
                                              const int* __restrict__ csr,
                                              const float* __restrict__ dis,
                                              const void* __restrict__ b,
                                              const void* __restrict__ Wn,
                                              const int* __restrict__ flagp,
                                              float4* __restrict__ out,
                                              float* __restrict__ tsn) {
    __shared__ float Wl[OUTF == 1 ? 32 : 1024];
    __shared__ float Xrow[4][32];
    int tid = threadIdx.x;
    int bf = *flagp;
    // stage next-layer weights (overlaps with gather; sync below covers it)
    if (OUTF == 32) {
        if (bf) {
            ushort4 h = ((const ushort4*)Wn)[tid];
            int p = tid * 4;
            Wl[p] = u2f(h.x); Wl[p + 1] = u2f(h.y); Wl[p + 2] = u2f(h.z); Wl[p + 3] = u2f(h.w);
        } else {
            float4 v = ((const float4*)Wn)[tid];
            int p = tid * 4;
            Wl[p] = v.x; Wl[p + 1] = v.y; Wl[p + 2] = v.z; Wl[p + 3] = v.w;
        }
    } else {
        if (tid < 32) Wl[tid] = LD(Wn, tid, bf);
    }

    int wid = tid >> 6;
    int node = blockIdx.x * 4 + wid;
    int lane = tid & 63;
    int q   = lane & 7;
    int grp = lane >> 3;
    int s = rs[node], e = re[node];
    float4 a0 = make_float4(0.f, 0.f, 0.f, 0.f);
    float4 a1 = a0, a2 = a0, a3 = a0;
    int i = s + grp;
    for (; i + 24 < e; i += 32) {
        int v0 = csr[i], v1 = csr[i + 8], v2 = csr[i + 16], v3 = csr[i + 24];
        float4 m0 = ts[v0 * 8 + q];
        float4 m1 = ts[v1 * 8 + q];
        float4 m2 = ts[v2 * 8 + q];
        float4 m3 = ts[v3 * 8 + q];
        a0.x += m0.x; a0.y += m0.y; a0.z += m0.z; a0.w += m0.w;
        a1.x += m1.x; a1.y += m1.y; a1.z += m1.z; a1.w += m1.w;
        a2.x += m2.x; a2.y += m2.y; a2.z += m2.z; a2.w += m2.w;
        a3.x += m3.x; a3.y += m3.y; a3.z += m3.z; a3.w += m3.w;
    }
    for (; i < e; i += 8) {
        float4 m = ts[csr[i] * 8 + q];
        a0.x += m.x; a0.y += m.y; a0.z += m.z; a0.w += m.w;
    }
    float4 acc;
    acc.x = (a0.x + a1.x) + (a2.x + a3.x);
    acc.y = (a0.y + a1.y) + (a2.y + a3.y);
    acc.z = (a0.z + a1.z) + (a2.z + a3.z);
    acc.w = (a0.w + a1.w) + (a2.w + a3.w);
#pragma unroll
    for (int off = 8; off < 64; off <<= 1) {
        acc.x += __shfl_xor(acc.x, off);
        acc.y += __shfl_xor(acc.y, off);
        acc.z += __shfl_xor(acc.z, off);
        acc.w += __shfl_xor(acc.w, off);
    }
    if (grp == 0) {
        float4 self = ts[node * 8 + q];
        float d = dis[node];
        vfloat4 r;
        r.x = tanhf(d * (acc.x + self.x) + LD(b, q * 4 + 0, bf));
        r.y = tanhf(d * (acc.y + self.y) + LD(b, q * 4 + 1, bf));
        r.z = tanhf(d * (acc.z + self.z) + LD(b, q * 4 + 2, bf));
        r.w = tanhf(d * (acc.w + self.w) + LD(b, q * 4 + 3, bf));
        __builtin_nontemporal_store(r, (vfloat4*)&out[node * 8 + q]);
        Xrow[wid][q * 4 + 0] = r.x;
        Xrow[wid][q * 4 + 1] = r.y;
        Xrow[wid][q * 4 + 2] = r.z;
        Xrow[wid][q * 4 + 3] = r.w;
    }
    __syncthreads();
    // ---- fused mm: tsn = dis * (Xrow @ Wn) ----
    if (OUTF == 32) {
        int nd = tid >> 6;                 // 0..3
        int col = tid & 31;
        int kbase = (tid & 32) >> 1;       // 0 or 16
        const float* xr = Xrow[nd];
        float a = 0.f;
#pragma unroll
        for (int k2 = 0; k2 < 16; k2++) a += xr[kbase + k2] * Wl[(kbase + k2) * 32 + col];
        a += __shfl_xor(a, 32);
        if (!(tid & 32)) {
            int n2 = blockIdx.x * 4 + nd;
            tsn[n2 * 32 + col] = dis[n2] * a;
        }
    } else {
        int g8 = tid >> 5;                 // 0..7; groups 0..3 active
        if (g8 < 4) {
            int n2 = blockIdx.x * 4 + g8;
            int k = tid & 31;
            float a = Xrow[g8][k] * Wl[k];
#pragma unroll
            for (int off = 16; off; off >>= 1) a += __shfl_xor(a, off);
            if (k == 0) tsn[n2] = dis[n2] * a;
        }
    }
}

// 16 lanes per node.
__global__ __launch_bounds__(256) void k_agg1(const float* __restrict__ ts4,
                                              const int* __restrict__ rs,
                                              const int* __restrict__ re,
                                              const int* __restrict__ csr,
                                              const float* __restrict__ dis,
                                              const void* __restrict__ b4,
                                              const int* __restrict__ flagp,
                                              float* __restrict__ x4) {
    int node = blockIdx.x * 16 + (threadIdx.x >> 4);
    int lane = threadIdx.x & 15;
    int s = rs[node], e = re[node];
    float acc = 0.f;
    for (int i = s + lane; i < e; i += 16) acc += ts4[csr[i]];
#pragma unroll
    for (int off = 1; off < 16; off <<= 1) acc += __shfl_xor(acc, off);
    if (lane == 0) {
        int bf = *flagp;
        x4[node] = tanhf(dis[node] * (acc + ts4[node]) + LD(b4, 0, bf));
    }
}

// ---------- SortPooling rank ----------
__global__ __launch_bounds__(256) void k_rank(const int* __restrict__ batch,
                                              const int* __restrict__ gstart,
                                              const float* __restrict__ x4,
                                              int* __restrict__ sel) {
    int i = blockIdx.x * 256 + threadIdx.x;
    if (i >= N_NODES) return;
    int g = batch[i];
    int s = gstart[g], e = gstart[g + 1];
    float ki = x4[i];
    int rank = 0;
    for (int j = s; j < e; j++) {
        float kj = x4[j];
        rank += (kj > ki) || (kj == ki && j < i);
    }
    if (rank < KTOP) sel[g * KTOP + rank] = i;
}

// ---------- Pooled-tensor gather ----------
__global__ __launch_bounds__(256) void k_pool(const float* __restrict__ x1,
                                              const float* __restrict__ x2,
                                              const float* __restrict__ x3,
                                              const float* __restrict__ x4,
                                              const int* __restrict__ sel,
                                              float* __restrict__ P) {
    int idx = blockIdx.x * 256 + threadIdx.x;
    if (idx >= PELEM) return;
    int g = idx / (KTOP * 97);
    int r = idx - g * (KTOP * 97);
    int p = r / 97;
    int f = r - p * 97;
    int v = sel[g * KTOP + p];
    float val = 0.f;
    if (v >= 0) {
        if (f < 32)      val = x1[v * 32 + f];
        else if (f < 64) val = x2[v * 32 + f - 32];
        else if (f < 96) val = x3[v * 32 + f - 64];
        else             val = x4[v];
    }
    P[idx] = val;
}

// ---------- CNN/MLP head: 256 threads, SIMPLE single-acc loops.
// Round-9 lesson: 4-way ILP + fc1 split => VGPR 132, occ 11%, 133 us. Keep
// per-thread register footprint small; win comes from 16 waves/CU vs 8. ----------
__global__ __launch_bounds__(256) void k_head(
    const float* __restrict__ Pg,
    const void* __restrict__ w5, const void* __restrict__ b5,
    const void* __restrict__ w6, const void* __restrict__ b6,
    const void* __restrict__ f1w, const void* __restrict__ f1b,
    const void* __restrict__ f2w, const void* __restrict__ f2b,
    const int* __restrict__ flagp, void* __restrict__ out) {
    __shared__ float P[KTOP * 97];
    __shared__ float W5[16 * 97];
    __shared__ float W6[32 * 16 * 5];
    __shared__ float H5[16][30];
    __shared__ float M[16][15];
    __shared__ float H6[352];
    __shared__ float Rp[256];
    __shared__ float R1[128];
    __shared__ float L[10];
    __shared__ float mls;
    int g = blockIdx.x;
    int tid = threadIdx.x;
    int bf = *flagp;

    for (int i = tid; i < KTOP * 97; i += 256) P[i] = Pg[g * (KTOP * 97) + i];
    if (bf) {   // vectorized bf16 weight staging
        const ushort4* w5v = (const ushort4*)w5;
        for (int i = tid; i < 388; i += 256) {           // 1552 = 388*4
            ushort4 h = w5v[i];
            int p = i * 4;
            W5[p] = u2f(h.x); W5[p + 1] = u2f(h.y); W5[p + 2] = u2f(h.z); W5[p + 3] = u2f(h.w);
        }
        const ushort4* w6v = (const ushort4*)w6;
        for (int i = tid; i < 640; i += 256) {           // 2560 = 640*4
            ushort4 h = w6v[i];
            int p = i * 4;
            W6[p] = u2f(h.x); W6[p + 1] = u2f(h.y); W6[p + 2] = u2f(h.z); W6[p + 3] = u2f(h.w);
        }
    } else {
        for (int i = tid; i < 16 * 97; i += 256) W5[i] = ((const float*)w5)[i];
        for (int i = tid; i < 2560; i += 256) W6[i] = ((const float*)w6)[i];
    }
    __syncthreads();
    for (int idx = tid; idx < 480; idx += 256) {   // conv5 + relu
        int o = idx / 30, p = idx - o * 30;
        float acc = LD(b5, o, bf);
        const float* pr = &P[p * 97];
        const float* wr = &W5[o * 97];
        for (int f = 0; f < 97; f++) acc += wr[f] * pr[f];
        H5[o][p] = fmaxf(acc, 0.f);
    }
    __syncthreads();
    for (int idx = tid; idx < 240; idx += 256) {   // maxpool2
        int o = idx / 15, q = idx - o * 15;
        M[o][q] = fmaxf(H5[o][2 * q], H5[o][2 * q + 1]);
    }
    __syncthreads();
    for (int idx = tid; idx < 352; idx += 256) {   // conv6 + relu
        int oc = idx / 11, tp = idx - oc * 11;
        float acc = LD(b6, oc, bf);
        const float* wr = &W6[oc * 80];
        for (int ic = 0; ic < 16; ic++) {
#pragma unroll
            for (int k = 0; k < 5; k++)
                acc += wr[ic * 5 + k] * M[ic][tp + k];
        }
        H6[idx] = fmaxf(acc, 0.f);
    }
    __syncthreads();
    {   // fc1: 2 threads per output column, 176 terms each, single accumulator
        int half = tid >> 7, col = tid & 127;
        int base = half * 176;
        float a = 0.f;
        for (int i = 0; i < 176; i++) {
            int ii = base + i;
            a += H6[ii] * LD(f1w, ii * 128 + col, bf);
        }
        Rp[tid] = a;
    }
    __syncthreads();
    if (tid < 128) R1[tid] = fmaxf(LD(f1b, tid, bf) + Rp[tid] + Rp[128 + tid], 0.f);
    __syncthreads();
    if (tid < 10) {   // fc2
        float acc = LD(f2b, tid, bf);
        for (int k = 0; k < 128; k++) acc += R1[k] * LD(f2w, k * 10 + tid, bf);
        L[tid] = acc;
    }
    __syncthreads();
    if (tid == 0) {
        float m = L[0];
        for (int c = 1; c < 10; c++) m = fmaxf(m, L[c]);
        float ssum = 0.f;
        for (int c = 0; c < 10; c++) ssum += expf(L[c] - m);
        mls = m + logf(ssum);
    }
    __syncthreads();
    if (tid < 10) {
        float v = L[tid] - mls;
        if (bf) ((bf16*)out)[g * 10 + tid] = __float2bfloat16(v);
        else    ((float*)out)[g * 10 + tid] = v;
    }
}

extern "C" void kernel_launch(void* const* d_in, const int* in_sizes, int n_in,
                              void* d_out, int out_size, void* d_ws, size_t ws_size,
                              hipStream_t stream) {
    const void* x   = d_in[0];
    const void* w1  = d_in[1];  const void* b1  = d_in[2];
    const void* w2  = d_in[3];  const void* b2  = d_in[4];
    const void* w3  = d_in[5];  const void* b3  = d_in[6];
    const void* w4  = d_in[7];  const void* b4  = d_in[8];
    const void* w5  = d_in[9];  const void* b5  = d_in[10];
    const void* w6  = d_in[11]; const void* b6  = d_in[12];
    const void* f1w = d_in[13]; const void* f1b = d_in[14];
    const void* f2w = d_in[15]; const void* f2b = d_in[16];
    const int* esrc  = (const int*)d_in[17];
    const int* edst  = (const int*)d_in[18];
    const int* batch = (const int*)d_in[19];

    char* w = (char*)d_ws;
    size_t off = 0;
    auto alloc = [&](size_t bytes) {
        void* p = w + off;
        off += (bytes + 255) & ~(size_t)255;
        return p;
    };
    int*   flag   = (int*)  alloc(256);
    int*   rs     = (int*)  alloc((size_t)N_NODES * 4);
    int*   re     = (int*)  alloc((size_t)N_NODES * 4);
    float* dis    = (float*)alloc((size_t)N_NODES * 4);
    int*   csr    = (int*)  alloc((size_t)NBKT * BKT_CAP * 4);
    float* t      = (float*)alloc((size_t)N_NODES * 32 * 4);   // ts ping (aliased by ebuf head)
    float* t2     = (float*)alloc((size_t)N_NODES * 32 * 4);   // ts pong
    float* x1     = (float*)alloc((size_t)N_NODES * 32 * 4);
    float* x2     = (float*)alloc((size_t)N_NODES * 32 * 4);
    float* x3     = (float*)alloc((size_t)N_NODES * 32 * 4);
    float* x4     = (float*)alloc((size_t)N_NODES * 4);
    int*   gstart = (int*)  alloc((size_t)(NGRAPH + 1) * 4);
    int*   sel    = (int*)  alloc((size_t)NGRAPH * KTOP * 4);
    float* Pg     = (float*)alloc((size_t)PELEM * 4);
    int*   cur    = (int*)  alloc((size_t)NBKT * 4);
    (void)ws_size; (void)n_in; (void)in_sizes; (void)out_size;

    // ebuf (padded bucketed packed edges, 14.8 MB) aliases t + head of t2,
    // both dead until k_mm1 / k_aggf layer 1.
    int* ebuf = (int*)t;

    (void)hipMemsetAsync(sel, 0xFF, (size_t)NGRAPH * KTOP * 4, stream);

    int nb   = (N_NODES + 255) / 256;
    int mb32 = N_NODES / 32;
    int ab   = N_NODES / 4;
    int a1b  = N_NODES / 16;
    int pb   = (PELEM + 255) / 256;

    k_detect<<<1, 64, 0, stream>>>(w1, flag);
    k_icur<<<(NBKT + 255) / 256, 256, 0, stream>>>(cur);
    k_scat<<<NTILE, 256, 0, stream>>>(esrc, edst, cur, ebuf);
    k_bcsr<<<NBKT, 256, 0, stream>>>(ebuf, cur, rs, re, dis, csr);
    k_gstart<<<5, 256, 0, stream>>>(batch, gstart);

    k_mm1<<<mb32, 256, 0, stream>>>(x, w1, flag, dis, t);
    // layer1: gather ts1(t) -> x1 ; fused ts2 = dis*(x1@w2) -> t2
    k_aggf<32><<<ab, 256, 0, stream>>>((const float4*)t,  rs, re, csr, dis, b1, w2, flag, (float4*)x1, t2);
    // layer2: gather ts2(t2) -> x2 ; fused ts3 = dis*(x2@w3) -> t
    k_aggf<32><<<ab, 256, 0, stream>>>((const float4*)t2, rs, re, csr, dis, b2, w3, flag, (float4*)x2, t);
    // layer3: gather ts3(t) -> x3 ; fused ts4 = dis*(x3@w4) -> t2
    k_aggf<1><<<ab, 256, 0, stream>>>((const float4*)t,  rs, re, csr, dis, b3, w4, flag, (float4*)x3, t2);
    k_agg1<<<a1b, 256, 0, stream>>>(t2, rs, re, csr, dis, b4, flag, x4);
    k_rank<<<nb, 256, 0, stream>>>(batch, gstart, x4, sel);
    k_pool<<<pb, 256, 0, stream>>>(x1, x2, x3, x4, sel, Pg);
    k_head<<<NGRAPH, 256, 0, stream>>>(Pg, w5, b5, w6, b6,
                                       f1w, f1b, f2w, f2b, flag, (void*)d_out);
}

// Round 5
// 561.772 us; speedup vs baseline: 1.1133x; 1.0453x over previous
//
#include <hip/hip_runtime.h>
#include <hip/hip_bf16.h>

#define N_NODES 100000
#define N_EDGES 3200000
#define NGRAPH 1024
#define KTOP 30
#define PELEM (NGRAPH * KTOP * 97)         // pooled tensor elements

#define NBKT 782                            // ceil(100000 / 128) node buckets
#define NTILE 391                            // edge tiles
#define TILE 8192                            // edges per tile (391*8192 >= 3.2M)
#define BKT_CAP 4736                         // padded bucket capacity (mean 4096 + 10 sigma)

typedef __hip_bfloat16 bf16;

__device__ __forceinline__ float u2f(unsigned short h) {
    return __uint_as_float(((unsigned int)h) << 16);
}
// Flag-steered scalar load of a float-tensor input that may be bf16 or f32.
__device__ __forceinline__ float LD(const void* p, int i, int bf) {
    if (bf) return u2f(((const unsigned short*)p)[i]);
    return ((const float*)p)[i];
}

// ---------- dtype probe ----------
__global__ void k_detect(const void* w1, int* flag) {
    if (threadIdx.x == 0 && blockIdx.x == 0) {
        const unsigned short* u = (const unsigned short*)w1;
        int plausible = 0;
        for (int i = 0; i < 64; i++) {
            float a = fabsf(u2f(u[2 * i]));
            if (a == 0.f || (a >= 9.765625e-4f && a <= 2.0f)) plausible++;
        }
        *flag = (plausible >= 40) ? 1 : 0;
    }
}

// ---------- one-pass padded-bucket edge partition ----------
__global__ void k_icur(int* __restrict__ cur) {
    int i = blockIdx.x * 256 + threadIdx.x;
    if (i < NBKT) cur[i] = i * BKT_CAP;
}

__global__ __launch_bounds__(256) void k_scat(const int* __restrict__ src,
                                              const int* __restrict__ dst,
                                              int* __restrict__ cur,
                                              int* __restrict__ ebuf) {
    __shared__ int pk[TILE];                 // 32 KB packed records
    __shared__ unsigned short bk[TILE];      // 16 KB bucket ids (0xFFFF = skip)
    __shared__ int h[NBKT];                  // per-tile histogram, then cursor
    __shared__ int base[NBKT];               // reserved global base per bucket
    int tid = threadIdx.x;
    int ebase = blockIdx.x * TILE;
    for (int i = tid; i < NBKT; i += 256) h[i] = 0;
    __syncthreads();
    for (int i = tid; i < TILE; i += 256) {
        int e = ebase + i;
        int bkt = 0xFFFF;
        if (e < N_EDGES) {
            int s = __builtin_nontemporal_load(src + e);
            int d = __builtin_nontemporal_load(dst + e);
            if (s != d) {
                bkt = d >> 7;
                pk[i] = ((d & 127) << 17) | s;
                atomicAdd(&h[bkt], 1);
            }
        }
        bk[i] = (unsigned short)bkt;
    }
    __syncthreads();
    for (int i = tid; i < NBKT; i += 256) {
        int c = h[i];
        base[i] = c ? atomicAdd(&cur[i], c) : 0;
    }
    __syncthreads();
    for (int i = tid; i < NBKT; i += 256) h[i] = 0;   // reuse as local cursors
    __syncthreads();
    for (int i = tid; i < TILE; i += 256) {
        int bkt = bk[i];
        if (bkt != 0xFFFF) {
            int p = base[bkt] + atomicAdd(&h[bkt], 1);
            if (p < (bkt + 1) * BKT_CAP) ebuf[p] = pk[i];   // overflow guard (never fires)
        }
    }
}

__global__ __launch_bounds__(256) void k_bcsr(const int* __restrict__ ebuf,
                                              const int* __restrict__ cur,
                                              int* __restrict__ rs,
                                              int* __restrict__ re,
                                              float* __restrict__ dis,
                                              int* __restrict__ csr) {
    __shared__ int dloc[128];
    __shared__ int sc[128];
    int b = blockIdx.x;
    int node0 = b << 7;
    int nn = N_NODES - node0; if (nn > 128) nn = 128;
    int tid = threadIdx.x;
    if (tid < 128) dloc[tid] = 0;
    __syncthreads();
    int s = b * BKT_CAP;
    int cnt = cur[b] - s; if (cnt > BKT_CAP) cnt = BKT_CAP;
    int e = s + cnt;
    for (int i = s + tid; i < e; i += 256)
        atomicAdd(&dloc[ebuf[i] >> 17], 1);
    __syncthreads();
    if (tid < 128) sc[tid] = dloc[tid];
    __syncthreads();
    for (int off = 1; off < 128; off <<= 1) {
        int t = (tid >= off && tid < 128) ? sc[tid - off] : 0;
        __syncthreads();
        if (tid < 128) sc[tid] += t;
        __syncthreads();
    }
    if (tid < nn) {
        int st = s + sc[tid] - dloc[tid];
        rs[node0 + tid] = st;
        re[node0 + tid] = st + dloc[tid];
        dis[node0 + tid] = rsqrtf((float)dloc[tid] + 1.0f);
    }
    __syncthreads();
    if (tid < 128) dloc[tid] = s + sc[tid] - dloc[tid];  // cursors
    __syncthreads();
    for (int i = s + tid; i < e; i += 256) {
        int pv = ebuf[i];
        int pos = atomicAdd(&dloc[pv >> 17], 1);
        csr[pos] = pv & 0x1FFFF;
    }
}

__global__ void k_gstart(const int* __restrict__ batch, int* __restrict__ gstart) {
    int g = blockIdx.x * 256 + threadIdx.x;
    if (g > NGRAPH) return;
    int lo = 0, hi = N_NODES;
    while (lo < hi) {
        int mid = (lo + hi) >> 1;
        if (batch[mid] < g) lo = mid + 1; else hi = mid;
    }
    gstart[g] = lo;
}

// ---------- GCN layer 1 matmul (ts1 = dis * (x @ W1)) ----------
__global__ __launch_bounds__(256) void k_mm1(const void* __restrict__ x,
                                             const void* __restrict__ w,
                                             const int* __restrict__ flagp,
                                             const float* __restrict__ dis,
                                             float* __restrict__ ts) {
    __shared__ float Wl[128 * 32];
    __shared__ float Xs[32][128];
    int bf = *flagp;
    int tid = threadIdx.x;
    int nbase = blockIdx.x * 32;          // N_NODES % 32 == 0: always full
    if (bf) {
        const ushort4* wv = (const ushort4*)w;
        for (int idx = tid; idx < 1024; idx += 256) {
            ushort4 h = wv[idx];
            int p = idx * 4;
            Wl[p] = u2f(h.x); Wl[p + 1] = u2f(h.y); Wl[p + 2] = u2f(h.z); Wl[p + 3] = u2f(h.w);
        }
        const ushort4* xv = (const ushort4*)x;
        for (int idx = tid; idx < 1024; idx += 256) {
            int nd = idx >> 5, q = idx & 31;
            ushort4 h = xv[(size_t)(nbase + nd) * 32 + q];
            float* d = &Xs[nd][q * 4];
            d[0] = u2f(h.x); d[1] = u2f(h.y); d[2] = u2f(h.z); d[3] = u2f(h.w);
        }
    } else {
        const float* wf = (const float*)w;
        for (int idx = tid; idx < 4096; idx += 256) Wl[idx] = wf[idx];
        const float* xf = (const float*)x;
        for (int idx = tid; idx < 4096; idx += 256)
            Xs[idx >> 7][idx & 127] = xf[(size_t)nbase * 128 + idx];
    }
    __syncthreads();
    int grp = tid >> 5, col = tid & 31;
    for (int rep = 0; rep < 4; rep++) {
        int sub = grp + 8 * rep;
        int node = nbase + sub;
        float acc = 0.f;
#pragma unroll 8
        for (int k = 0; k < 128; k++) acc += Xs[sub][k] * Wl[k * 32 + col];
        ts[node * 32 + col] = dis[node] * acc;
    }
}

// ---------- Layer-1 aggregate: gather pre-multiplied ts1 rows, tanh, write x1 ----------
// One wave64 per node; 8 lanes per row (float4/lane); gather loop unrolled x4.
__global__ __launch_bounds__(256) void k_agg(const float4* __restrict__ ts,
                                             const int* __restrict__ rs,
                                             const int* __restrict__ re,
                                             const int* __restrict__ csr,
                                             const float* __restrict__ dis,
                                             const void* __restrict__ b,
                                             const int* __restrict__ flagp,
                                             float4* __restrict__ out) {
    int node = blockIdx.x * 4 + (threadIdx.x >> 6);
    int lane = threadIdx.x & 63;
    int q   = lane & 7;
    int grp = lane >> 3;
    int bf = *flagp;
    int s = rs[node], e = re[node];
    float4 a0 = make_float4(0.f, 0.f, 0.f, 0.f);
    float4 a1 = a0, a2 = a0, a3 = a0;
    int i = s + grp;
    for (; i + 24 < e; i += 32) {
        int v0 = csr[i], v1 = csr[i + 8], v2 = csr[i + 16], v3 = csr[i + 24];
        float4 m0 = ts[v0 * 8 + q];
        float4 m1 = ts[v1 * 8 + q];
        float4 m2 = ts[v2 * 8 + q];
        float4 m3 = ts[v3 * 8 + q];
        a0.x += m0.x; a0.y += m0.y; a0.z += m0.z; a0.w += m0.w;
        a1.x += m1.x; a1.y += m1.y; a1.z += m1.z; a1.w += m1.w;
        a2.x += m2.x; a2.y += m2.y; a2.z += m2.z; a2.w += m2.w;
        a3.x += m3.x; a3.y += m3.y; a3.z += m3.z; a3.w += m3.w;
    }
    for (; i < e; i += 8) {
        float4 m = ts[csr[i] * 8 + q];
        a0.x += m.x; a0.y += m.y; a0.z += m.z; a0.w += m.w;
    }
    float4 acc;
    acc.x = (a0.x + a1.x) + (a2.x + a3.x);
    acc.y = (a0.y + a1.y) + (a2.y + a3.y);
    acc.z = (a0.z + a1.z) + (a2.z + a3.z);
    acc.w = (a0.w + a1.w) + (a2.w + a3.w);
#pragma unroll
    for (int off = 8; off < 64; off <<= 1) {
        acc.x += __shfl_xor(acc.x, off);
        acc.y += __shfl_xor(acc.y, off);
        acc.z += __shfl_xor(acc.z, off);
        acc.w += __shfl_xor(acc.w, off);
    }
    if (grp == 0) {
        float4 self = ts[node * 8 + q];
        float d = dis[node];
        float4 r;
        r.x = tanhf(d * (acc.x + self.x) + LD(b, q * 4 + 0, bf));
        r.y = tanhf(d * (acc.y + self.y) + LD(b, q * 4 + 1, bf));
        r.z = tanhf(d * (acc.z + self.z) + LD(b, q * 4 + 2, bf));
        r.w = tanhf(d * (acc.w + self.w) + LD(b, q * 4 + 3, bf));
        out[node * 8 + q] = r;
    }
}

// ---------- Layers 2/3: gather RAW x rows with per-edge dis scale, then post-gather mm.
// z_i = sum_src dis_src*x_src + dis_i*x_i ; x_out = tanh(dis_i*(z@W)+b).
// Saves the 12.5 MB tsn intermediate write per layer (round-4 lesson: the fused
// pre-multiply write doubled WRITE_SIZE on an L2-fill-bound kernel).
// DO_TS4: epilogue also emits ts4 = dis*(x_out@w4) (0.4 MB) for k_agg1.
template<int DO_TS4>
__global__ __launch_bounds__(256) void k_aggz(const float4* __restrict__ xin,
                                              const int* __restrict__ rs,
                                              const int* __restrict__ re,
                                              const int* __restrict__ csr,
                                              const float* __restrict__ dis,
                                              const void* __restrict__ W,
                                              const void* __restrict__ b,
                                              const void* __restrict__ w4,
                                              const int* __restrict__ flagp,
                                              float* __restrict__ xout,
                                              float* __restrict__ ts4) {
    __shared__ float Wl[1024];
    __shared__ float W4l[32];
    __shared__ float Z[4][32];
    int tid = threadIdx.x;
    int bf = *flagp;
    if (bf) {
        ushort4 h = ((const ushort4*)W)[tid];
        int p = tid * 4;
        Wl[p] = u2f(h.x); Wl[p + 1] = u2f(h.y); Wl[p + 2] = u2f(h.z); Wl[p + 3] = u2f(h.w);
    } else {
        float4 v = ((const float4*)W)[tid];
        int p = tid * 4;
        Wl[p] = v.x; Wl[p + 1] = v.y; Wl[p + 2] = v.z; Wl[p + 3] = v.w;
    }
    if (DO_TS4 && tid < 32) W4l[tid] = LD(w4, tid, bf);

    int wid = tid >> 6;
    int node = blockIdx.x * 4 + wid;
    int lane = tid & 63;
    int q   = lane & 7;
    int grp = lane >> 3;
    int s = rs[node], e = re[node];
    float4 a0 = make_float4(0.f, 0.f, 0.f, 0.f);
    float4 a1 = a0, a2 = a0, a3 = a0;
    int i = s + grp;
    for (; i + 24 < e; i += 32) {
        int v0 = csr[i], v1 = csr[i + 8], v2 = csr[i + 16], v3 = csr[i + 24];
        float d0 = dis[v0], d1 = dis[v1], d2 = dis[v2], d3 = dis[v3];
        float4 m0 = xin[v0 * 8 + q];
        float4 m1 = xin[v1 * 8 + q];
        float4 m2 = xin[v2 * 8 + q];
        float4 m3 = xin[v3 * 8 + q];
        a0.x += d0 * m0.x; a0.y += d0 * m0.y; a0.z += d0 * m0.z; a0.w += d0 * m0.w;
        a1.x += d1 * m1.x; a1.y += d1 * m1.y; a1.z += d1 * m1.z; a1.w += d1 * m1.w;
        a2.x += d2 * m2.x; a2.y += d2 * m2.y; a2.z += d2 * m2.z; a2.w += d2 * m2.w;
        a3.x += d3 * m3.x; a3.y += d3 * m3.y; a3.z += d3 * m3.z; a3.w += d3 * m3.w;
    }
    for (; i < e; i += 8) {
        int v = csr[i];
        float dv = dis[v];
        float4 m = xin[v * 8 + q];
        a0.x += dv * m.x; a0.y += dv * m.y; a0.z += dv * m.z; a0.w += dv * m.w;
    }
    float4 acc;
    acc.x = (a0.x + a1.x) + (a2.x + a3.x);
    acc.y = (a0.y + a1.y) + (a2.y + a3.y);
    acc.z = (a0.z + a1.z) + (a2.z + a3.z);
    acc.w = (a0.w + a1.w) + (a2.w + a3.w);
#pragma unroll
    for (int off = 8; off < 64; off <<= 1) {
        acc.x += __shfl_xor(acc.x, off);
        acc.y += __shfl_xor(acc.y, off);
        acc.z += __shfl_xor(acc.z, off);
        acc.w += __shfl_xor(acc.w, off);
    }
    if (grp == 0) {
        float4 self = xin[node * 8 + q];
        float di = dis[node];
        Z[wid][q * 4 + 0] = acc.x + di * self.x;
        Z[wid][q * 4 + 1] = acc.y + di * self.y;
        Z[wid][q * 4 + 2] = acc.z + di * self.z;
        Z[wid][q * 4 + 3] = acc.w + di * self.w;
    }
    __syncthreads();
    // ---- post-gather mm: x_out = tanh(dis*(Z@W)+b) ----
    int nd = tid >> 6;                 // node slot 0..3
    int col = tid & 31;
    int kbase = (tid & 32) >> 1;       // 0 or 16
    const float* zr = Z[nd];
    float a = 0.f;
#pragma unroll
    for (int k2 = 0; k2 < 16; k2++) a += zr[kbase + k2] * Wl[(kbase + k2) * 32 + col];
    a += __shfl_xor(a, 32);            // both halves now hold full dot
    int n2 = blockIdx.x * 4 + nd;
    float di2 = dis[n2];
    float xo = tanhf(di2 * a + LD(b, col, bf));
    if (!(tid & 32)) xout[n2 * 32 + col] = xo;
    if (DO_TS4) {
        float t4 = xo * W4l[col];      // identical in both halves
#pragma unroll
        for (int off = 1; off < 32; off <<= 1) t4 += __shfl_xor(t4, off);
        if ((tid & 63) == 0) ts4[n2] = di2 * t4;
    }
}

// 16 lanes per node.
__global__ __launch_bounds__(256) void k_agg1(const float* __restrict__ ts4,
                                              const int* __restrict__ rs,
                                              const int* __restrict__ re,
                                              const int* __restrict__ csr,
                                              const float* __restrict__ dis,
                                              const void* __restrict__ b4,
                                              const int* __restrict__ flagp,
                                              float* __restrict__ x4) {
    int node = blockIdx.x * 16 + (threadIdx.x >> 4);
    int lane = threadIdx.x & 15;
    int s = rs[node], e = re[node];
    float acc = 0.f;
    for (int i = s + lane; i < e; i += 16) acc += ts4[csr[i]];
#pragma unroll
    for (int off = 1; off < 16; off <<= 1) acc += __shfl_xor(acc, off);
    if (lane == 0) {
        int bf = *flagp;
        x4[node] = tanhf(dis[node] * (acc + ts4[node]) + LD(b4, 0, bf));
    }
}

// ---------- SortPooling rank ----------
__global__ __launch_bounds__(256) void k_rank(const int* __restrict__ batch,
                                              const int* __restrict__ gstart,
                                              const float* __restrict__ x4,
                                              int* __restrict__ sel) {
    int i = blockIdx.x * 256 + threadIdx.x;
    if (i >= N_NODES) return;
    int g = batch[i];
    int s = gstart[g], e = gstart[g + 1];
    float ki = x4[i];
    int rank = 0;
    for (int j = s; j < e; j++) {
        float kj = x4[j];
        rank += (kj > ki) || (kj == ki && j < i);
    }
    if (rank < KTOP) sel[g * KTOP + rank] = i;
}

// ---------- Pooled-tensor gather ----------
__global__ __launch_bounds__(256) void k_pool(const float* __restrict__ x1,
                                              const float* __restrict__ x2,
                                              const float* __restrict__ x3,
                                              const float* __restrict__ x4,
                                              const int* __restrict__ sel,
                                              float* __restrict__ P) {
    int idx = blockIdx.x * 256 + threadIdx.x;
    if (idx >= PELEM) return;
    int g = idx / (KTOP * 97);
    int r = idx - g * (KTOP * 97);
    int p = r / 97;
    int f = r - p * 97;
    int v = sel[g * KTOP + p];
    float val = 0.f;
    if (v >= 0) {
        if (f < 32)      val = x1[v * 32 + f];
        else if (f < 64) val = x2[v * 32 + f - 32];
        else if (f < 96) val = x3[v * 32 + f - 64];
        else             val = x4[v];
    }
    P[idx] = val;
}

// ---------- CNN/MLP head: 256 threads, SIMPLE single-acc loops. ----------
__global__ __launch_bounds__(256) void k_head(
    const float* __restrict__ Pg,
    const void* __restrict__ w5, const void* __restrict__ b5,
    const void* __restrict__ w6, const void* __restrict__ b6,
    const void* __restrict__ f1w, const void* __restrict__ f1b,
    const void* __restrict__ f2w, const void* __restrict__ f2b,
    const int* __restrict__ flagp, void* __restrict__ out) {
    __shared__ float P[KTOP * 97];
    __shared__ float W5[16 * 97];
    __shared__ float W6[32 * 16 * 5];
    __shared__ float H5[16][30];
    __shared__ float M[16][15];
    __shared__ float H6[352];
    __shared__ float Rp[256];
    __shared__ float R1[128];
    __shared__ float L[10];
    __shared__ float mls;
    int g = blockIdx.x;
    int tid = threadIdx.x;
    int bf = *flagp;

    for (int i = tid; i < KTOP * 97; i += 256) P[i] = Pg[g * (KTOP * 97) + i];
    if (bf) {   // vectorized bf16 weight staging
        const ushort4* w5v = (const ushort4*)w5;
        for (int i = tid; i < 388; i += 256) {           // 1552 = 388*4
            ushort4 h = w5v[i];
            int p = i * 4;
            W5[p] = u2f(h.x); W5[p + 1] = u2f(h.y); W5[p + 2] = u2f(h.z); W5[p + 3] = u2f(h.w);
        }
        const ushort4* w6v = (const ushort4*)w6;
        for (int i = tid; i < 640; i += 256) {           // 2560 = 640*4
            ushort4 h = w6v[i];
            int p = i * 4;
            W6[p] = u2f(h.x); W6[p + 1] = u2f(h.y); W6[p + 2] = u2f(h.z); W6[p + 3] = u2f(h.w);
        }
    } else {
        for (int i = tid; i < 16 * 97; i += 256) W5[i] = ((const float*)w5)[i];
        for (int i = tid; i < 2560; i += 256) W6[i] = ((const float*)w6)[i];
    }
    __syncthreads();
    for (int idx = tid; idx < 480; idx += 256) {   // conv5 + relu
        int o = idx / 30, p = idx - o * 30;
        float acc = LD(b5, o, bf);
        const float* pr = &P[p * 97];
        const float* wr = &W5[o * 97];
        for (int f = 0; f < 97; f++) acc += wr[f] * pr[f];
        H5[o][p] = fmaxf(acc, 0.f);
    }
    __syncthreads();
    for (int idx = tid; idx < 240; idx += 256) {   // maxpool2
        int o = idx / 15, q = idx - o * 15;
        M[o][q] = fmaxf(H5[o][2 * q], H5[o][2 * q + 1]);
    }
    __syncthreads();
    for (int idx = tid; idx < 352; idx += 256) {   // conv6 + relu
        int oc = idx / 11, tp = idx - oc * 11;
        float acc = LD(b6, oc, bf);
        const float* wr = &W6[oc * 80];
        for (int ic = 0; ic < 16; ic++) {
#pragma unroll
            for (int k = 0; k < 5; k++)
                acc += wr[ic * 5 + k] * M[ic][tp + k];
        }
        H6[idx] = fmaxf(acc, 0.f);
    }
    __syncthreads();
    {   // fc1: 2 threads per output column, 176 terms each, single accumulator
        int half = tid >> 7, col = tid & 127;
        int base = half * 176;
        float a = 0.f;
        for (int i = 0; i < 176; i++) {
            int ii = base + i;
            a += H6[ii] * LD(f1w, ii * 128 + col, bf);
        }
        Rp[tid] = a;
    }
    __syncthreads();
    if (tid < 128) R1[tid] = fmaxf(LD(f1b, tid, bf) + Rp[tid] + Rp[128 + tid], 0.f);
    __syncthreads();
    if (tid < 10) {   // fc2
        float acc = LD(f2b, tid, bf);
        for (int k = 0; k < 128; k++) acc += R1[k] * LD(f2w, k * 10 + tid, bf);
        L[tid] = acc;
    }
    __syncthreads();
    if (tid == 0) {
        float m = L[0];
        for (int c = 1; c < 10; c++) m = fmaxf(m, L[c]);
        float ssum = 0.f;
        for (int c = 0; c < 10; c++) ssum += expf(L[c] - m);
        mls = m + logf(ssum);
    }
    __syncthreads();
    if (tid < 10) {
        float v = L[tid] - mls;
        if (bf) ((bf16*)out)[g * 10 + tid] = __float2bfloat16(v);
        else    ((float*)out)[g * 10 + tid] = v;
    }
}

extern "C" void kernel_launch(void* const* d_in, const int* in_sizes, int n_in,
                              void* d_out, int out_size, void* d_ws, size_t ws_size,
                              hipStream_t stream) {
    const void* x   = d_in[0];
    const void* w1  = d_in[1];  const void* b1  = d_in[2];
    const void* w2  = d_in[3];  const void* b2  = d_in[4];
    const void* w3  = d_in[5];  const void* b3  = d_in[6];
    const void* w4  = d_in[7];  const void* b4  = d_in[8];
    const void* w5  = d_in[9];  const void* b5  = d_in[10];
    const void* w6  = d_in[11]; const void* b6  = d_in[12];
    const void* f1w = d_in[13]; const void* f1b = d_in[14];
    const void* f2w = d_in[15]; const void* f2b = d_in[16];
    const int* esrc  = (const int*)d_in[17];
    const int* edst  = (const int*)d_in[18];
    const int* batch = (const int*)d_in[19];

    char* w = (char*)d_ws;
    size_t off = 0;
    auto alloc = [&](size_t bytes) {
        void* p = w + off;
        off += (bytes + 255) & ~(size_t)255;
        return p;
    };
    int*   flag   = (int*)  alloc(256);
    int*   rs     = (int*)  alloc((size_t)N_NODES * 4);
    int*   re     = (int*)  alloc((size_t)N_NODES * 4);
    float* dis    = (float*)alloc((size_t)N_NODES * 4);
    int*   csr    = (int*)  alloc((size_t)NBKT * BKT_CAP * 4);
    float* t      = (float*)alloc((size_t)N_NODES * 32 * 4);   // ts1 (aliased by ebuf head)
    float* x1     = (float*)alloc((size_t)N_NODES * 32 * 4);
    float* x2     = (float*)alloc((size_t)N_NODES * 32 * 4);
    float* x3     = (float*)alloc((size_t)N_NODES * 32 * 4);
    float* x4     = (float*)alloc((size_t)N_NODES * 4);
    float* ts4b   = (float*)alloc((size_t)N_NODES * 4);
    int*   gstart = (int*)  alloc((size_t)(NGRAPH + 1) * 4);
    int*   sel    = (int*)  alloc((size_t)NGRAPH * KTOP * 4);
    float* Pg     = (float*)alloc((size_t)PELEM * 4);
    int*   cur    = (int*)  alloc((size_t)NBKT * 4);
    (void)ws_size; (void)n_in; (void)in_sizes; (void)out_size;

    // ebuf (padded bucketed packed edges, 14.8 MB) aliases t + head of x1,
    // both dead until k_mm1 / k_agg layer 1.
    int* ebuf = (int*)t;

    (void)hipMemsetAsync(sel, 0xFF, (size_t)NGRAPH * KTOP * 4, stream);

    int nb   = (N_NODES + 255) / 256;
    int mb32 = N_NODES / 32;
    int ab   = N_NODES / 4;
    int a1b  = N_NODES / 16;
    int pb   = (PELEM + 255) / 256;

    k_detect<<<1, 64, 0, stream>>>(w1, flag);
    k_icur<<<(NBKT + 255) / 256, 256, 0, stream>>>(cur);
    k_scat<<<NTILE, 256, 0, stream>>>(esrc, edst, cur, ebuf);
    k_bcsr<<<NBKT, 256, 0, stream>>>(ebuf, cur, rs, re, dis, csr);
    k_gstart<<<5, 256, 0, stream>>>(batch, gstart);

    k_mm1<<<mb32, 256, 0, stream>>>(x, w1, flag, dis, t);
    // layer1: gather ts1 -> x1
    k_agg<<<ab, 256, 0, stream>>>((const float4*)t, rs, re, csr, dis, b1, flag, (float4*)x1);
    // layer2: gather x1 (per-edge dis) -> z ; x2 = tanh(dis*(z@w2)+b2)
    k_aggz<0><<<ab, 256, 0, stream>>>((const float4*)x1, rs, re, csr, dis, w2, b2, w4, flag, x2, ts4b);
    // layer3: gather x2 -> z ; x3 = tanh(dis*(z@w3)+b3) ; ts4 = dis*(x3@w4)
    k_aggz<1><<<ab, 256, 0, stream>>>((const float4*)x2, rs, re, csr, dis, w3, b3, w4, flag, x3, ts4b);
    k_agg1<<<a1b, 256, 0, stream>>>(ts4b, rs, re, csr, dis, b4, flag, x4);
    k_rank<<<nb, 256, 0, stream>>>(batch, gstart, x4, sel);
    k_pool<<<pb, 256, 0, stream>>>(x1, x2, x3, x4, sel, Pg);
    k_head<<<NGRAPH, 256, 0, stream>>>(Pg, w5, b5, w6, b6,
                                       f1w, f1b, f2w, f2b, flag, (void*)d_out);
}

// Round 6
// 561.252 us; speedup vs baseline: 1.1143x; 1.0009x over previous
//
#include <hip/hip_runtime.h>
#include <hip/hip_bf16.h>

#define N_NODES 100000
#define N_EDGES 3200000
#define NGRAPH 1024
#define KTOP 30
#define PELEM (NGRAPH * KTOP * 97)         // pooled tensor elements

#define NBKT 782                            // ceil(100000 / 128) node buckets
#define NTILE 391                            // edge tiles
#define TILE 8192                            // edges per tile (391*8192 >= 3.2M)
#define BKT_CAP 4736                         // padded bucket capacity (mean 4096 + 10 sigma)

typedef __hip_bfloat16 bf16;
typedef float vfloat4 __attribute__((ext_vector_type(4)));   // native vec for nt-store

__device__ __forceinline__ float u2f(unsigned short h) {
    return __uint_as_float(((unsigned int)h) << 16);
}
// Flag-steered scalar load of a float-tensor input that may be bf16 or f32.
__device__ __forceinline__ float LD(const void* p, int i, int bf) {
    if (bf) return u2f(((const unsigned short*)p)[i]);
    return ((const float*)p)[i];
}

// ---------- dtype probe ----------
__global__ void k_detect(const void* w1, int* flag) {
    if (threadIdx.x == 0 && blockIdx.x == 0) {
        const unsigned short* u = (const unsigned short*)w1;
        int plausible = 0;
        for (int i = 0; i < 64; i++) {
            float a = fabsf(u2f(u[2 * i]));
            if (a == 0.f || (a >= 9.765625e-4f && a <= 2.0f)) plausible++;
        }
        *flag = (plausible >= 40) ? 1 : 0;
    }
}

// ---------- one-pass padded-bucket edge partition ----------
__global__ void k_icur(int* __restrict__ cur) {
    int i = blockIdx.x * 256 + threadIdx.x;
    if (i < NBKT) cur[i] = i * BKT_CAP;
}

__global__ __launch_bounds__(256) void k_scat(const int* __restrict__ src,
                                              const int* __restrict__ dst,
                                              int* __restrict__ cur,
                                              int* __restrict__ ebuf) {
    __shared__ int pk[TILE];                 // 32 KB packed records
    __shared__ unsigned short bk[TILE];      // 16 KB bucket ids (0xFFFF = skip)
    __shared__ int h[NBKT];                  // per-tile histogram, then cursor
    __shared__ int base[NBKT];               // reserved global base per bucket
    int tid = threadIdx.x;
    int ebase = blockIdx.x * TILE;
    for (int i = tid; i < NBKT; i += 256) h[i] = 0;
    __syncthreads();
    for (int i = tid; i < TILE; i += 256) {
        int e = ebase + i;
        int bkt = 0xFFFF;
        if (e < N_EDGES) {
            int s = __builtin_nontemporal_load(src + e);
            int d = __builtin_nontemporal_load(dst + e);
            if (s != d) {
                bkt = d >> 7;
                pk[i] = ((d & 127) << 17) | s;
                atomicAdd(&h[bkt], 1);
            }
        }
        bk[i] = (unsigned short)bkt;
    }
    __syncthreads();
    for (int i = tid; i < NBKT; i += 256) {
        int c = h[i];
        base[i] = c ? atomicAdd(&cur[i], c) : 0;
    }
    __syncthreads();
    for (int i = tid; i < NBKT; i += 256) h[i] = 0;   // reuse as local cursors
    __syncthreads();
    for (int i = tid; i < TILE; i += 256) {
        int bkt = bk[i];
        if (bkt != 0xFFFF) {
            int p = base[bkt] + atomicAdd(&h[bkt], 1);
            if (p < (bkt + 1) * BKT_CAP) ebuf[p] = pk[i];   // overflow guard (never fires)
        }
    }
}

// ---------- bucket counts -> rs/re/dis/deg (pass 1 of old k_bcsr) ----------
__global__ __launch_bounds__(256) void k_bcnt(const int* __restrict__ ebuf,
                                              const int* __restrict__ cur,
                                              int* __restrict__ rs,
                                              int* __restrict__ re,
                                              float* __restrict__ dis,
                                              int* __restrict__ deg) {
    __shared__ int dloc[128];
    __shared__ int sc[128];
    int b = blockIdx.x;
    int node0 = b << 7;
    int nn = N_NODES - node0; if (nn > 128) nn = 128;
    int tid = threadIdx.x;
    if (tid < 128) dloc[tid] = 0;
    __syncthreads();
    int s = b * BKT_CAP;
    int cnt = cur[b] - s; if (cnt > BKT_CAP) cnt = BKT_CAP;
    int e = s + cnt;
    for (int i = s + tid; i < e; i += 256)
        atomicAdd(&dloc[ebuf[i] >> 17], 1);
    __syncthreads();
    if (tid < 128) sc[tid] = dloc[tid];
    __syncthreads();
    for (int off = 1; off < 128; off <<= 1) {
        int t = (tid >= off && tid < 128) ? sc[tid - off] : 0;
        __syncthreads();
        if (tid < 128) sc[tid] += t;
        __syncthreads();
    }
    if (tid < nn) {
        int st = s + sc[tid] - dloc[tid];
        rs[node0 + tid] = st;
        re[node0 + tid] = st + dloc[tid];
        dis[node0 + tid] = rsqrtf((float)dloc[tid] + 1.0f);
        deg[node0 + tid] = dloc[tid];
    }
}

// ---------- fill csr with deg-packed entries: (deg[src]<<17)|src (pass 2) ----------
__global__ __launch_bounds__(256) void k_bfill(const int* __restrict__ ebuf,
                                               const int* __restrict__ cur,
                                               const int* __restrict__ rs,
                                               const int* __restrict__ deg,
                                               int* __restrict__ csr) {
    __shared__ int cl[128];
    int b = blockIdx.x;
    int node0 = b << 7;
    int tid = threadIdx.x;
    if (tid < 128) {
        int n = node0 + tid;
        cl[tid] = (n < N_NODES) ? rs[n] : 0;
    }
    __syncthreads();
    int s = b * BKT_CAP;
    int cnt = cur[b] - s; if (cnt > BKT_CAP) cnt = BKT_CAP;
    int e = s + cnt;
    for (int i = s + tid; i < e; i += 256) {
        int pv = ebuf[i];
        int srcn = pv & 0x1FFFF;
        int pos = atomicAdd(&cl[pv >> 17], 1);
        int d = deg[srcn];                   // L2-resident 400KB gather
        csr[pos] = (d << 17) | srcn;         // deg < 2^15 on this graph family
    }
}

__global__ void k_gstart(const int* __restrict__ batch, int* __restrict__ gstart) {
    int g = blockIdx.x * 256 + threadIdx.x;
    if (g > NGRAPH) return;
    int lo = 0, hi = N_NODES;
    while (lo < hi) {
        int mid = (lo + hi) >> 1;
        if (batch[mid] < g) lo = mid + 1; else hi = mid;
    }
    gstart[g] = lo;
}

// ---------- GCN layer 1 matmul (ts1 = dis * (x @ W1)) ----------
// Register-blocked: 64 nodes/block, thread = 4 nodes x 2 cols => 1.5 B LDS/FMA
// (old form was 8 B/FMA, LDS-throughput-bound ~3.3 GB). Each output is still a
// single f32 FMA chain over ascending k => bit-identical results.
#define MM1_B 64
__global__ __launch_bounds__(256) void k_mm1(const void* __restrict__ x,
                                             const void* __restrict__ w,
                                             const int* __restrict__ flagp,
                                             const float* __restrict__ dis,
                                             float* __restrict__ ts) {
    __shared__ float Xs[MM1_B][129];        // pad 129: 4-row lane stride = 2-way conflict only
    __shared__ float Wf[128 * 32];
    int bf = *flagp;
    int tid = threadIdx.x;
    int nbase = blockIdx.x * MM1_B;
    if (bf) {
        const ushort4* wv = (const ushort4*)w;
        for (int idx = tid; idx < 1024; idx += 256) {
            ushort4 h = wv[idx];
            int p = idx * 4;
            Wf[p] = u2f(h.x); Wf[p + 1] = u2f(h.y); Wf[p + 2] = u2f(h.z); Wf[p + 3] = u2f(h.w);
        }
        const unsigned short* xb = (const unsigned short*)x;
        for (int idx = tid; idx < 1024; idx += 256) {     // 64 rows * 16 ushort8
            int row = idx >> 4, c8 = (idx & 15) * 8;
            int gn = nbase + row; if (gn >= N_NODES) gn = N_NODES - 1;
            uint4 v = *(const uint4*)(xb + (size_t)gn * 128 + c8);
            float* d = &Xs[row][c8];
            d[0] = u2f((unsigned short)(v.x & 0xffff)); d[1] = u2f((unsigned short)(v.x >> 16));
            d[2] = u2f((unsigned short)(v.y & 0xffff)); d[3] = u2f((unsigned short)(v.y >> 16));
            d[4] = u2f((unsigned short)(v.z & 0xffff)); d[5] = u2f((unsigned short)(v.z >> 16));
            d[6] = u2f((unsigned short)(v.w & 0xffff)); d[7] = u2f((unsigned short)(v.w >> 16));
        }
    } else {
        const float* wf = (const float*)w;
        for (int idx = tid; idx < 4096; idx += 256) Wf[idx] = wf[idx];
        const float4* xv = (const float4*)x;
        for (int idx = tid; idx < 2048; idx += 256) {     // 64 rows * 32 float4
            int row = idx >> 5, c4 = (idx & 31) * 4;
            int gn = nbase + row; if (gn >= N_NODES) gn = N_NODES - 1;
            float4 v = xv[(size_t)gn * 32 + (c4 >> 2)];
            float* d = &Xs[row][c4];
            d[0] = v.x; d[1] = v.y; d[2] = v.z; d[3] = v.w;
        }
    }
    __syncthreads();
    int tn = (tid & 15) * 4;          // 4 consecutive node rows
    int tc = (tid >> 4) * 2;          // 2 consecutive cols
    float a00 = 0.f, a01 = 0.f, a10 = 0.f, a11 = 0.f;
    float a20 = 0.f, a21 = 0.f, a30 = 0.f, a31 = 0.f;
#pragma unroll 4
    for (int k = 0; k < 128; k++) {
        float2 wv = *(const float2*)&Wf[k * 32 + tc];
        float x0 = Xs[tn + 0][k], x1 = Xs[tn + 1][k];
        float x2 = Xs[tn + 2][k], x3 = Xs[tn + 3][k];
        a00 += x0 * wv.x; a01 += x0 * wv.y;
        a10 += x1 * wv.x; a11 += x1 * wv.y;
        a20 += x2 * wv.x; a21 += x2 * wv.y;
        a30 += x3 * wv.x; a31 += x3 * wv.y;
    }
    int n0 = nbase + tn;
    if (n0 + 0 < N_NODES) { float d = dis[n0 + 0]; *(float2*)&ts[(n0 + 0) * 32 + tc] = make_float2(d * a00, d * a01); }
    if (n0 + 1 < N_NODES) { float d = dis[n0 + 1]; *(float2*)&ts[(n0 + 1) * 32 + tc] = make_float2(d * a10, d * a11); }
    if (n0 + 2 < N_NODES) { float d = dis[n0 + 2]; *(float2*)&ts[(n0 + 2) * 32 + tc] = make_float2(d * a20, d * a21); }
    if (n0 + 3 < N_NODES) { float d = dis[n0 + 3]; *(float2*)&ts[(n0 + 3) * 32 + tc] = make_float2(d * a30, d * a31); }
}

// ---------- Layer-1 aggregate: gather pre-multiplied ts1 rows, tanh, write x1 ----------
__global__ __launch_bounds__(256) void k_agg(const float4* __restrict__ ts,
                                             const int* __restrict__ rs,
                                             const int* __restrict__ re,
                                             const int* __restrict__ csr,
                                             const float* __restrict__ dis,
                                             const void* __restrict__ b,
                                             const int* __restrict__ flagp,
                                             float4* __restrict__ out) {
    int node = blockIdx.x * 4 + (threadIdx.x >> 6);
    int lane = threadIdx.x & 63;
    int q   = lane & 7;
    int grp = lane >> 3;
    int bf = *flagp;
    int s = rs[node], e = re[node];
    float4 a0 = make_float4(0.f, 0.f, 0.f, 0.f);
    float4 a1 = a0, a2 = a0, a3 = a0;
    int i = s + grp;
    for (; i + 24 < e; i += 32) {
        int v0 = csr[i] & 0x1FFFF, v1 = csr[i + 8] & 0x1FFFF;
        int v2 = csr[i + 16] & 0x1FFFF, v3 = csr[i + 24] & 0x1FFFF;
        float4 m0 = ts[v0 * 8 + q];
        float4 m1 = ts[v1 * 8 + q];
        float4 m2 = ts[v2 * 8 + q];
        float4 m3 = ts[v3 * 8 + q];
        a0.x += m0.x; a0.y += m0.y; a0.z += m0.z; a0.w += m0.w;
        a1.x += m1.x; a1.y += m1.y; a1.z += m1.z; a1.w += m1.w;
        a2.x += m2.x; a2.y += m2.y; a2.z += m2.z; a2.w += m2.w;
        a3.x += m3.x; a3.y += m3.y; a3.z += m3.z; a3.w += m3.w;
    }
    for (; i < e; i += 8) {
        float4 m = ts[(csr[i] & 0x1FFFF) * 8 + q];
        a0.x += m.x; a0.y += m.y; a0.z += m.z; a0.w += m.w;
    }
    float4 acc;
    acc.x = (a0.x + a1.x) + (a2.x + a3.x);
    acc.y = (a0.y + a1.y) + (a2.y + a3.y);
    acc.z = (a0.z + a1.z) + (a2.z + a3.z);
    acc.w = (a0.w + a1.w) + (a2.w + a3.w);
#pragma unroll
    for (int off = 8; off < 64; off <<= 1) {
        acc.x += __shfl_xor(acc.x, off);
        acc.y += __shfl_xor(acc.y, off);
        acc.z += __shfl_xor(acc.z, off);
        acc.w += __shfl_xor(acc.w, off);
    }
    if (grp == 0) {
        float4 self = ts[node * 8 + q];
        float d = dis[node];
        vfloat4 r;
        r.x = tanhf(d * (acc.x + self.x) + LD(b, q * 4 + 0, bf));
        r.y = tanhf(d * (acc.y + self.y) + LD(b, q * 4 + 1, bf));
        r.z = tanhf(d * (acc.z + self.z) + LD(b, q * 4 + 2, bf));
        r.w = tanhf(d * (acc.w + self.w) + LD(b, q * 4 + 3, bf));
        __builtin_nontemporal_store(r, (vfloat4*)&out[node * 8 + q]);
    }
}

// ---------- Layers 2/3: gather RAW x rows; dis_src from deg packed in csr.
// dis_src = rsqrtf(deg+1) — same v_rsq_f32 on same input as stored dis => bit-identical.
template<int DO_TS4>
__global__ __launch_bounds__(256) void k_aggz(const float4* __restrict__ xin,
                                              const int* __restrict__ rs,
                                              const int* __restrict__ re,
                                              const int* __restrict__ csr,
                                              const float* __restrict__ dis,
                                              const void* __restrict__ W,
                                              const void* __restrict__ b,
                                              const void* __restrict__ w4,
                                              const int* __restrict__ flagp,
                                              float* __restrict__ xout,
                                              float* __restrict__ ts4) {
    __shared__ float Wl[1024];
    __shared__ float W4l[32];
    __shared__ float Z[4][32];
    int tid = threadIdx.x;
    int bf = *flagp;
    if (bf) {
        ushort4 h = ((const ushort4*)W)[tid];
        int p = tid * 4;
        Wl[p] = u2f(h.x); Wl[p + 1] = u2f(h.y); Wl[p + 2] = u2f(h.z); Wl[p + 3] = u2f(h.w);
    } else {
        float4 v = ((const float4*)W)[tid];
        int p = tid * 4;
        Wl[p] = v.x; Wl[p + 1] = v.y; Wl[p + 2] = v.z; Wl[p + 3] = v.w;
    }
    if (DO_TS4 && tid < 32) W4l[tid] = LD(w4, tid, bf);

    int wid = tid >> 6;
    int node = blockIdx.x * 4 + wid;
    int lane = tid & 63;
    int q   = lane & 7;
    int grp = lane >> 3;
    int s = rs[node], e = re[node];
    float4 a0 = make_float4(0.f, 0.f, 0.f, 0.f);
    float4 a1 = a0, a2 = a0, a3 = a0;
    int i = s + grp;
    for (; i + 24 < e; i += 32) {
        int p0 = csr[i], p1 = csr[i + 8], p2 = csr[i + 16], p3 = csr[i + 24];
        int v0 = p0 & 0x1FFFF, v1 = p1 & 0x1FFFF, v2 = p2 & 0x1FFFF, v3 = p3 & 0x1FFFF;
        float d0 = rsqrtf((float)(p0 >> 17) + 1.0f);
        float d1 = rsqrtf((float)(p1 >> 17) + 1.0f);
        float d2 = rsqrtf((float)(p2 >> 17) + 1.0f);
        float d3 = rsqrtf((float)(p3 >> 17) + 1.0f);
        float4 m0 = xin[v0 * 8 + q];
        float4 m1 = xin[v1 * 8 + q];
        float4 m2 = xin[v2 * 8 + q];
        float4 m3 = xin[v3 * 8 + q];
        a0.x += d0 * m0.x; a0.y += d0 * m0.y; a0.z += d0 * m0.z; a0.w += d0 * m0.w;
        a1.x += d1 * m1.x; a1.y += d1 * m1.y; a1.z += d1 * m1.z; a1.w += d1 * m1.w;
        a2.x += d2 * m2.x; a2.y += d2 * m2.y; a2.z += d2 * m2.z; a2.w += d2 * m2.w;
        a3.x += d3 * m3.x; a3.y += d3 * m3.y; a3.z += d3 * m3.z; a3.w += d3 * m3.w;
    }
    for (; i < e; i += 8) {
        int pv = csr[i];
        int v = pv & 0x1FFFF;
        float dv = rsqrtf((float)(pv >> 17) + 1.0f);
        float4 m = xin[v * 8 + q];
        a0.x += dv * m.x; a0.y += dv * m.y; a0.z += dv * m.z; a0.w += dv * m.w;
    }
    float4 acc;
    acc.x = (a0.x + a1.x) + (a2.x + a3.x);
    acc.y = (a0.y + a1.y) + (a2.y + a3.y);
    acc.z = (a0.z + a1.z) + (a2.z + a3.z);
    acc.w = (a0.w + a1.w) + (a2.w + a3.w);
#pragma unroll
    for (int off = 8; off < 64; off <<= 1) {
        acc.x += __shfl_xor(acc.x, off);
        acc.y += __shfl_xor(acc.y, off);
        acc.z += __shfl_xor(acc.z, off);
        acc.w += __shfl_xor(acc.w, off);
    }
    if (grp == 0) {
        float4 self = xin[node * 8 + q];
        float di = dis[node];
        Z[wid][q * 4 + 0] = acc.x + di * self.x;
        Z[wid][q * 4 + 1] = acc.y + di * self.y;
        Z[wid][q * 4 + 2] = acc.z + di * self.z;
        Z[wid][q * 4 + 3] = acc.w + di * self.w;
    }
    __syncthreads();
    // ---- post-gather mm: x_out = tanh(dis*(Z@W)+b) ----
    int nd = tid >> 6;                 // node slot 0..3
    int col = tid & 31;
    int kbase = (tid & 32) >> 1;       // 0 or 16
    const float* zr = Z[nd];
    float a = 0.f;
#pragma unroll
    for (int k2 = 0; k2 < 16; k2++) a += zr[kbase + k2] * Wl[(kbase + k2) * 32 + col];
    a += __shfl_xor(a, 32);            // both halves now hold full dot
    int n2 = blockIdx.x * 4 + nd;
    float di2 = dis[n2];
    float xo = tanhf(di2 * a + LD(b, col, bf));
    if (!(tid & 32)) xout[n2 * 32 + col] = xo;
    if (DO_TS4) {
        float t4 = xo * W4l[col];      // identical in both halves
#pragma unroll
        for (int off = 1; off < 32; off <<= 1) t4 += __shfl_xor(t4, off);
        if ((tid & 63) == 0) ts4[n2] = di2 * t4;
    }
}

// 16 lanes per node.
__global__ __launch_bounds__(256) void k_agg1(const float* __restrict__ ts4,
                                              const int* __restrict__ rs,
                                              const int* __restrict__ re,
                                              const int* __restrict__ csr,
                                              const float* __restrict__ dis,
                                              const void* __restrict__ b4,
                                              const int* __restrict__ flagp,
                                              float* __restrict__ x4) {
    int node = blockIdx.x * 16 + (threadIdx.x >> 4);
    int lane = threadIdx.x & 15;
    int s = rs[node], e = re[node];
    float acc = 0.f;
    for (int i = s + lane; i < e; i += 16) acc += ts4[csr[i] & 0x1FFFF];
#pragma unroll
    for (int off = 1; off < 16; off <<= 1) acc += __shfl_xor(acc, off);
    if (lane == 0) {
        int bf = *flagp;
        x4[node] = tanhf(dis[node] * (acc + ts4[node]) + LD(b4, 0, bf));
    }
}

// ---------- SortPooling rank ----------
__global__ __launch_bounds__(256) void k_rank(const int* __restrict__ batch,
                                              const int* __restrict__ gstart,
                                              const float* __restrict__ x4,
                                              int* __restrict__ sel) {
    int i = blockIdx.x * 256 + threadIdx.x;
    if (i >= N_NODES) return;
    int g = batch[i];
    int s = gstart[g], e = gstart[g + 1];
    float ki = x4[i];
    int rank = 0;
    for (int j = s; j < e; j++) {
        float kj = x4[j];
        rank += (kj > ki) || (kj == ki && j < i);
    }
    if (rank < KTOP) sel[g * KTOP + rank] = i;
}

// ---------- Pooled-tensor gather ----------
__global__ __launch_bounds__(256) void k_pool(const float* __restrict__ x1,
                                              const float* __restrict__ x2,
                                              const float* __restrict__ x3,
                                              const float* __restrict__ x4,
                                              const int* __restrict__ sel,
                                              float* __restrict__ P) {
    int idx = blockIdx.x * 256 + threadIdx.x;
    if (idx >= PELEM) return;
    int g = idx / (KTOP * 97);
    int r = idx - g * (KTOP * 97);
    int p = r / 97;
    int f = r - p * 97;
    int v = sel[g * KTOP + p];
    float val = 0.f;
    if (v >= 0) {
        if (f < 32)      val = x1[v * 32 + f];
        else if (f < 64) val = x2[v * 32 + f - 32];
        else if (f < 96) val = x3[v * 32 + f - 64];
        else             val = x4[v];
    }
    P[idx] = val;
}

// ---------- CNN/MLP head: 256 threads, SIMPLE single-acc loops. ----------
__global__ __launch_bounds__(256) void k_head(
    const float* __restrict__ Pg,
    const void* __restrict__ w5, const void* __restrict__ b5,
    const void* __restrict__ w6, const void* __restrict__ b6,
    const void* __restrict__ f1w, const void* __restrict__ f1b,
    const void* __restrict__ f2w, const void* __restrict__ f2b,
    const int* __restrict__ flagp, void* __restrict__ out) {
    __shared__ float P[KTOP * 97];
    __shared__ float W5[16 * 97];
    __shared__ float W6[32 * 16 * 5];
    __shared__ float H5[16][30];
    __shared__ float M[16][15];
    __shared__ float H6[352];
    __shared__ float Rp[256];
    __shared__ float R1[128];
    __shared__ float L[10];
    __shared__ float mls;
    int g = blockIdx.x;
    int tid = threadIdx.x;
    int bf = *flagp;

    for (int i = tid; i < KTOP * 97; i += 256) P[i] = Pg[g * (KTOP * 97) + i];
    if (bf) {   // vectorized bf16 weight staging
        const ushort4* w5v = (const ushort4*)w5;
        for (int i = tid; i < 388; i += 256) {           // 1552 = 388*4
            ushort4 h = w5v[i];
            int p = i * 4;
            W5[p] = u2f(h.x); W5[p + 1] = u2f(h.y); W5[p + 2] = u2f(h.z); W5[p + 3] = u2f(h.w);
        }
        const ushort4* w6v = (const ushort4*)w6;
        for (int i = tid; i < 640; i += 256) {           // 2560 = 640*4
            ushort4 h = w6v[i];
            int p = i * 4;
            W6[p] = u2f(h.x); W6[p + 1] = u2f(h.y); W6[p + 2] = u2f(h.z); W6[p + 3] = u2f(h.w);
        }
    } else {
        for (int i = tid; i < 16 * 97; i += 256) W5[i] = ((const float*)w5)[i];
        for (int i = tid; i < 2560; i += 256) W6[i] = ((const float*)w6)[i];
    }
    __syncthreads();
    for (int idx = tid; idx < 480; idx += 256) {   // conv5 + relu
        int o = idx / 30, p = idx - o * 30;
        float acc = LD(b5, o, bf);
        const float* pr = &P[p * 97];
        const float* wr = &W5[o * 97];
        for (int f = 0; f < 97; f++) acc += wr[f] * pr[f];
        H5[o][p] = fmaxf(acc, 0.f);
    }
    __syncthreads();
    for (int idx = tid; idx < 240; idx += 256) {   // maxpool2
        int o = idx / 15, q = idx - o * 15;
        M[o][q] = fmaxf(H5[o][2 * q], H5[o][2 * q + 1]);
    }
    __syncthreads();
    for (int idx = tid; idx < 352; idx += 256) {   // conv6 + relu
        int oc = idx / 11, tp = idx - oc * 11;
        float acc = LD(b6, oc, bf);
        const float* wr = &W6[oc * 80];
        for (int ic = 0; ic < 16; ic++) {
#pragma unroll
            for (int k = 0; k < 5; k++)
                acc += wr[ic * 5 + k] * M[ic][tp + k];
        }
        H6[idx] = fmaxf(acc, 0.f);
    }
    __syncthreads();
    {   // fc1: 2 threads per output column, 176 terms each, single accumulator
        int half = tid >> 7, col = tid & 127;
        int base = half * 176;
        float a = 0.f;
        for (int i = 0; i < 176; i++) {
            int ii = base + i;
            a += H6[ii] * LD(f1w, ii * 128 + col, bf);
        }
        Rp[tid] = a;
    }
    __syncthreads();
    if (tid < 128) R1[tid] = fmaxf(LD(f1b, tid, bf) + Rp[tid] + Rp[128 + tid], 0.f);
    __syncthreads();
    if (tid < 10) {   // fc2
        float acc = LD(f2b, tid, bf);
        for (int k = 0; k < 128; k++) acc += R1[k] * LD(f2w, k * 10 + tid, bf);
        L[tid] = acc;
    }
    __syncthreads();
    if (tid == 0) {
        float m = L[0];
        for (int c = 1; c < 10; c++) m = fmaxf(m, L[c]);
        float ssum = 0.f;
        for (int c = 0; c < 10; c++) ssum += expf(L[c] - m);
        mls = m + logf(ssum);
    }
    __syncthreads();
    if (tid < 10) {
        float v = L[tid] - mls;
        if (bf) ((bf16*)out)[g * 10 + tid] = __float2bfloat16(v);
        else    ((float*)out)[g * 10 + tid] = v;
    }
}

extern "C" void kernel_launch(void* const* d_in, const int* in_sizes, int n_in,
                              void* d_out, int out_size, void* d_ws, size_t ws_size,
                              hipStream_t stream) {
    const void* x   = d_in[0];
    const void* w1  = d_in[1];  const void* b1  = d_in[2];
    const void* w2  = d_in[3];  const void* b2  = d_in[4];
    const void* w3  = d_in[5];  const void* b3  = d_in[6];
    const void* w4  = d_in[7];  const void* b4  = d_in[8];
    const void* w5  = d_in[9];  const void* b5  = d_in[10];
    const void* w6  = d_in[11]; const void* b6  = d_in[12];
    const void* f1w = d_in[13]; const void* f1b = d_in[14];
    const void* f2w = d_in[15]; const void* f2b = d_in[16];
    const int* esrc  = (const int*)d_in[17];
    const int* edst  = (const int*)d_in[18];
    const int* batch = (const int*)d_in[19];

    char* w = (char*)d_ws;
    size_t off = 0;
    auto alloc = [&](size_t bytes) {
        void* p = w + off;
        off += (bytes + 255) & ~(size_t)255;
        return p;
    };
    int*   flag   = (int*)  alloc(256);
    int*   rs     = (int*)  alloc((size_t)N_NODES * 4);
    int*   re     = (int*)  alloc((size_t)N_NODES * 4);
    float* dis    = (float*)alloc((size_t)N_NODES * 4);
    int*   deg    = (int*)  alloc((size_t)N_NODES * 4);
    int*   csr    = (int*)  alloc((size_t)NBKT * BKT_CAP * 4);
    float* t      = (float*)alloc((size_t)N_NODES * 32 * 4);   // ts1 (aliased by ebuf head)
    float* x1     = (float*)alloc((size_t)N_NODES * 32 * 4);
    float* x2     = (float*)alloc((size_t)N_NODES * 32 * 4);
    float* x3     = (float*)alloc((size_t)N_NODES * 32 * 4);
    float* x4     = (float*)alloc((size_t)N_NODES * 4);
    float* ts4b   = (float*)alloc((size_t)N_NODES * 4);
    int*   gstart = (int*)  alloc((size_t)(NGRAPH + 1) * 4);
    int*   sel    = (int*)  alloc((size_t)NGRAPH * KTOP * 4);
    float* Pg     = (float*)alloc((size_t)PELEM * 4);
    int*   cur    = (int*)  alloc((size_t)NBKT * 4);
    (void)ws_size; (void)n_in; (void)in_sizes; (void)out_size;

    // ebuf (padded bucketed packed edges, 14.8 MB) aliases t + head of x1,
    // both dead until k_mm1 / k_agg layer 1.
    int* ebuf = (int*)t;

    (void)hipMemsetAsync(sel, 0xFF, (size_t)NGRAPH * KTOP * 4, stream);

    int nb   = (N_NODES + 255) / 256;
    int mb64 = (N_NODES + MM1_B - 1) / MM1_B;
    int ab   = N_NODES / 4;
    int a1b  = N_NODES / 16;
    int pb   = (PELEM + 255) / 256;

    k_detect<<<1, 64, 0, stream>>>(w1, flag);
    k_icur<<<(NBKT + 255) / 256, 256, 0, stream>>>(cur);
    k_scat<<<NTILE, 256, 0, stream>>>(esrc, edst, cur, ebuf);
    k_bcnt<<<NBKT, 256, 0, stream>>>(ebuf, cur, rs, re, dis, deg);
    k_bfill<<<NBKT, 256, 0, stream>>>(ebuf, cur, rs, deg, csr);
    k_gstart<<<5, 256, 0, stream>>>(batch, gstart);

    k_mm1<<<mb64, 256, 0, stream>>>(x, w1, flag, dis, t);
    // layer1: gather ts1 -> x1
    k_agg<<<ab, 256, 0, stream>>>((const float4*)t, rs, re, csr, dis, b1, flag, (float4*)x1);
    // layer2: gather x1 (deg-packed dis) -> z ; x2 = tanh(dis*(z@w2)+b2)
    k_aggz<0><<<ab, 256, 0, stream>>>((const float4*)x1, rs, re, csr, dis, w2, b2, w4, flag, x2, ts4b);
    // layer3: gather x2 -> z ; x3 = tanh(dis*(z@w3)+b3) ; ts4 = dis*(x3@w4)
    k_aggz<1><<<ab, 256, 0, stream>>>((const float4*)x2, rs, re, csr, dis, w3, b3, w4, flag, x3, ts4b);
    k_agg1<<<a1b, 256, 0, stream>>>(ts4b, rs, re, csr, dis, b4, flag, x4);
    k_rank<<<nb, 256, 0, stream>>>(batch, gstart, x4, sel);
    k_pool<<<pb, 256, 0, stream>>>(x1, x2, x3, x4, sel, Pg);
    k_head<<<NGRAPH, 256, 0, stream>>>(Pg, w5, b5, w6, b6,
                                       f1w, f1b, f2w, f2b, flag, (void*)d_out);
}

// Round 7
// 538.413 us; speedup vs baseline: 1.1616x; 1.0424x over previous
//
#include <hip/hip_runtime.h>
#include <hip/hip_bf16.h>

#define N_NODES 100000
#define N_EDGES 3200000
#define NGRAPH 1024
#define KTOP 30

#define NBKT 782                            // ceil(100000 / 128) node buckets
#define NTILE 391                            // edge tiles
#define TILE 8192                            // edges per tile (391*8192 >= 3.2M)
#define BKT_CAP 4736                         // padded bucket capacity (mean 4096 + 10 sigma)
#define GMAX 512                             // per-graph node cap for LDS keys (mean 98, +40 sigma)

typedef __hip_bfloat16 bf16;
typedef float vfloat4 __attribute__((ext_vector_type(4)));   // native vec for nt-store

__device__ __forceinline__ float u2f(unsigned short h) {
    return __uint_as_float(((unsigned int)h) << 16);
}
// Flag-steered scalar load of a float-tensor input that may be bf16 or f32.
__device__ __forceinline__ float LD(const void* p, int i, int bf) {
    if (bf) return u2f(((const unsigned short*)p)[i]);
    return ((const float*)p)[i];
}

// ---------- dtype probe ----------
__global__ void k_detect(const void* w1, int* flag) {
    if (threadIdx.x == 0 && blockIdx.x == 0) {
        const unsigned short* u = (const unsigned short*)w1;
        int plausible = 0;
        for (int i = 0; i < 64; i++) {
            float a = fabsf(u2f(u[2 * i]));
            if (a == 0.f || (a >= 9.765625e-4f && a <= 2.0f)) plausible++;
        }
        *flag = (plausible >= 40) ? 1 : 0;
    }
}

// ---------- one-pass padded-bucket edge partition ----------
__global__ void k_icur(int* __restrict__ cur) {
    int i = blockIdx.x * 256 + threadIdx.x;
    if (i < NBKT) cur[i] = i * BKT_CAP;
}

__global__ __launch_bounds__(256) void k_scat(const int* __restrict__ src,
                                              const int* __restrict__ dst,
                                              int* __restrict__ cur,
                                              int* __restrict__ ebuf) {
    __shared__ int pk[TILE];                 // 32 KB packed records
    __shared__ unsigned short bk[TILE];      // 16 KB bucket ids (0xFFFF = skip)
    __shared__ int h[NBKT];                  // per-tile histogram, then cursor
    __shared__ int base[NBKT];               // reserved global base per bucket
    int tid = threadIdx.x;
    int ebase = blockIdx.x * TILE;
    for (int i = tid; i < NBKT; i += 256) h[i] = 0;
    __syncthreads();
    for (int i = tid; i < TILE; i += 256) {
        int e = ebase + i;
        int bkt = 0xFFFF;
        if (e < N_EDGES) {
            int s = __builtin_nontemporal_load(src + e);
            int d = __builtin_nontemporal_load(dst + e);
            if (s != d) {
                bkt = d >> 7;
                pk[i] = ((d & 127) << 17) | s;
                atomicAdd(&h[bkt], 1);
            }
        }
        bk[i] = (unsigned short)bkt;
    }
    __syncthreads();
    for (int i = tid; i < NBKT; i += 256) {
        int c = h[i];
        base[i] = c ? atomicAdd(&cur[i], c) : 0;
    }
    __syncthreads();
    for (int i = tid; i < NBKT; i += 256) h[i] = 0;   // reuse as local cursors
    __syncthreads();
    for (int i = tid; i < TILE; i += 256) {
        int bkt = bk[i];
        if (bkt != 0xFFFF) {
            int p = base[bkt] + atomicAdd(&h[bkt], 1);
            if (p < (bkt + 1) * BKT_CAP) ebuf[p] = pk[i];   // overflow guard (never fires)
        }
    }
}

// ---------- bucket counts -> rs/re/dis/deg ----------
__global__ __launch_bounds__(256) void k_bcnt(const int* __restrict__ ebuf,
                                              const int* __restrict__ cur,
                                              int* __restrict__ rs,
                                              int* __restrict__ re,
                                              float* __restrict__ dis,
                                              int* __restrict__ deg) {
    __shared__ int dloc[128];
    __shared__ int sc[128];
    int b = blockIdx.x;
    int node0 = b << 7;
    int nn = N_NODES - node0; if (nn > 128) nn = 128;
    int tid = threadIdx.x;
    if (tid < 128) dloc[tid] = 0;
    __syncthreads();
    int s = b * BKT_CAP;
    int cnt = cur[b] - s; if (cnt > BKT_CAP) cnt = BKT_CAP;
    int e = s + cnt;
    for (int i = s + tid; i < e; i += 256)
        atomicAdd(&dloc[ebuf[i] >> 17], 1);
    __syncthreads();
    if (tid < 128) sc[tid] = dloc[tid];
    __syncthreads();
    for (int off = 1; off < 128; off <<= 1) {
        int t = (tid >= off && tid < 128) ? sc[tid - off] : 0;
        __syncthreads();
        if (tid < 128) sc[tid] += t;
        __syncthreads();
    }
    if (tid < nn) {
        int st = s + sc[tid] - dloc[tid];
        rs[node0 + tid] = st;
        re[node0 + tid] = st + dloc[tid];
        dis[node0 + tid] = rsqrtf((float)dloc[tid] + 1.0f);
        deg[node0 + tid] = dloc[tid];
    }
}

// ---------- fill csr with deg-packed entries: (deg[src]<<17)|src ----------
__global__ __launch_bounds__(256) void k_bfill(const int* __restrict__ ebuf,
                                               const int* __restrict__ cur,
                                               const int* __restrict__ rs,
                                               const int* __restrict__ deg,
                                               int* __restrict__ csr) {
    __shared__ int cl[128];
    int b = blockIdx.x;
    int node0 = b << 7;
    int tid = threadIdx.x;
    if (tid < 128) {
        int n = node0 + tid;
        cl[tid] = (n < N_NODES) ? rs[n] : 0;
    }
    __syncthreads();
    int s = b * BKT_CAP;
    int cnt = cur[b] - s; if (cnt > BKT_CAP) cnt = BKT_CAP;
    int e = s + cnt;
    for (int i = s + tid; i < e; i += 256) {
        int pv = ebuf[i];
        int srcn = pv & 0x1FFFF;
        int pos = atomicAdd(&cl[pv >> 17], 1);
        int d = deg[srcn];                   // L2-resident 400KB gather
        csr[pos] = (d << 17) | srcn;         // deg < 2^15 on this graph family
    }
}

__global__ void k_gstart(const int* __restrict__ batch, int* __restrict__ gstart) {
    int g = blockIdx.x * 256 + threadIdx.x;
    if (g > NGRAPH) return;
    int lo = 0, hi = N_NODES;
    while (lo < hi) {
        int mid = (lo + hi) >> 1;
        if (batch[mid] < g) lo = mid + 1; else hi = mid;
    }
    gstart[g] = lo;
}

// ---------- GCN layer 1 matmul (ts1 = dis * (x @ W1)) ----------
#define MM1_B 64
__global__ __launch_bounds__(256) void k_mm1(const void* __restrict__ x,
                                             const void* __restrict__ w,
                                             const int* __restrict__ flagp,
                                             const float* __restrict__ dis,
                                             float* __restrict__ ts) {
    __shared__ float Xs[MM1_B][129];        // pad 129: 4-row lane stride = 2-way conflict only
    __shared__ float Wf[128 * 32];
    int bf = *flagp;
    int tid = threadIdx.x;
    int nbase = blockIdx.x * MM1_B;
    if (bf) {
        const ushort4* wv = (const ushort4*)w;
        for (int idx = tid; idx < 1024; idx += 256) {
            ushort4 h = wv[idx];
            int p = idx * 4;
            Wf[p] = u2f(h.x); Wf[p + 1] = u2f(h.y); Wf[p + 2] = u2f(h.z); Wf[p + 3] = u2f(h.w);
        }
        const unsigned short* xb = (const unsigned short*)x;
        for (int idx = tid; idx < 1024; idx += 256) {     // 64 rows * 16 ushort8
            int row = idx >> 4, c8 = (idx & 15) * 8;
            int gn = nbase + row; if (gn >= N_NODES) gn = N_NODES - 1;
            uint4 v = *(const uint4*)(xb + (size_t)gn * 128 + c8);
            float* d = &Xs[row][c8];
            d[0] = u2f((unsigned short)(v.x & 0xffff)); d[1] = u2f((unsigned short)(v.x >> 16));
            d[2] = u2f((unsigned short)(v.y & 0xffff)); d[3] = u2f((unsigned short)(v.y >> 16));
            d[4] = u2f((unsigned short)(v.z & 0xffff)); d[5] = u2f((unsigned short)(v.z >> 16));
            d[6] = u2f((unsigned short)(v.w & 0xffff)); d[7] = u2f((unsigned short)(v.w >> 16));
        }
    } else {
        const float* wf = (const float*)w;
        for (int idx = tid; idx < 4096; idx += 256) Wf[idx] = wf[idx];
        const float4* xv = (const float4*)x;
        for (int idx = tid; idx < 2048; idx += 256) {     // 64 rows * 32 float4
            int row = idx >> 5, c4 = (idx & 31) * 4;
            int gn = nbase + row; if (gn >= N_NODES) gn = N_NODES - 1;
            float4 v = xv[(size_t)gn * 32 + (c4 >> 2)];
            float* d = &Xs[row][c4];
            d[0] = v.x; d[1] = v.y; d[2] = v.z; d[3] = v.w;
        }
    }
    __syncthreads();
    int tn = (tid & 15) * 4;          // 4 consecutive node rows
    int tc = (tid >> 4) * 2;          // 2 consecutive cols
    float a00 = 0.f, a01 = 0.f, a10 = 0.f, a11 = 0.f;
    float a20 = 0.f, a21 = 0.f, a30 = 0.f, a31 = 0.f;
#pragma unroll 4
    for (int k = 0; k < 128; k++) {
        float2 wv = *(const float2*)&Wf[k * 32 + tc];
        float x0 = Xs[tn + 0][k], x1 = Xs[tn + 1][k];
        float x2 = Xs[tn + 2][k], x3 = Xs[tn + 3][k];
        a00 += x0 * wv.x; a01 += x0 * wv.y;
        a10 += x1 * wv.x; a11 += x1 * wv.y;
        a20 += x2 * wv.x; a21 += x2 * wv.y;
        a30 += x3 * wv.x; a31 += x3 * wv.y;
    }
    int n0 = nbase + tn;
    if (n0 + 0 < N_NODES) { float d = dis[n0 + 0]; *(float2*)&ts[(n0 + 0) * 32 + tc] = make_float2(d * a00, d * a01); }
    if (n0 + 1 < N_NODES) { float d = dis[n0 + 1]; *(float2*)&ts[(n0 + 1) * 32 + tc] = make_float2(d * a10, d * a11); }
    if (n0 + 2 < N_NODES) { float d = dis[n0 + 2]; *(float2*)&ts[(n0 + 2) * 32 + tc] = make_float2(d * a20, d * a21); }
    if (n0 + 3 < N_NODES) { float d = dis[n0 + 3]; *(float2*)&ts[(n0 + 3) * 32 + tc] = make_float2(d * a30, d * a31); }
}

// ---------- Layer-1 aggregate: gather pre-multiplied ts1 rows, tanh, write x1 ----------
__global__ __launch_bounds__(256) void k_agg(const float4* __restrict__ ts,
                                             const int* __restrict__ rs,
                                             const int* __restrict__ re,
                                             const int* __restrict__ csr,
                                             const float* __restrict__ dis,
                                             const void* __restrict__ b,
                                             const int* __restrict__ flagp,
                                             float4* __restrict__ out) {
    int node = blockIdx.x * 4 + (threadIdx.x >> 6);
    int lane = threadIdx.x & 63;
    int q   = lane & 7;
    int grp = lane >> 3;
    int bf = *flagp;
    int s = rs[node], e = re[node];
    float4 a0 = make_float4(0.f, 0.f, 0.f, 0.f);
    float4 a1 = a0, a2 = a0, a3 = a0;
    int i = s + grp;
    for (; i + 24 < e; i += 32) {
        int v0 = csr[i] & 0x1FFFF, v1 = csr[i + 8] & 0x1FFFF;
        int v2 = csr[i + 16] & 0x1FFFF, v3 = csr[i + 24] & 0x1FFFF;
        float4 m0 = ts[v0 * 8 + q];
        float4 m1 = ts[v1 * 8 + q];
        float4 m2 = ts[v2 * 8 + q];
        float4 m3 = ts[v3 * 8 + q];
        a0.x += m0.x; a0.y += m0.y; a0.z += m0.z; a0.w += m0.w;
        a1.x += m1.x; a1.y += m1.y; a1.z += m1.z; a1.w += m1.w;
        a2.x += m2.x; a2.y += m2.y; a2.z += m2.z; a2.w += m2.w;
        a3.x += m3.x; a3.y += m3.y; a3.z += m3.z; a3.w += m3.w;
    }
    for (; i < e; i += 8) {
        float4 m = ts[(csr[i] & 0x1FFFF) * 8 + q];
        a0.x += m.x; a0.y += m.y; a0.z += m.z; a0.w += m.w;
    }
    float4 acc;
    acc.x = (a0.x + a1.x) + (a2.x + a3.x);
    acc.y = (a0.y + a1.y) + (a2.y + a3.y);
    acc.z = (a0.z + a1.z) + (a2.z + a3.z);
    acc.w = (a0.w + a1.w) + (a2.w + a3.w);
#pragma unroll
    for (int off = 8; off < 64; off <<= 1) {
        acc.x += __shfl_xor(acc.x, off);
        acc.y += __shfl_xor(acc.y, off);
        acc.z += __shfl_xor(acc.z, off);
        acc.w += __shfl_xor(acc.w, off);
    }
    if (grp == 0) {
        float4 self = ts[node * 8 + q];
        float d = dis[node];
        vfloat4 r;
        r.x = tanhf(d * (acc.x + self.x) + LD(b, q * 4 + 0, bf));
        r.y = tanhf(d * (acc.y + self.y) + LD(b, q * 4 + 1, bf));
        r.z = tanhf(d * (acc.z + self.z) + LD(b, q * 4 + 2, bf));
        r.w = tanhf(d * (acc.w + self.w) + LD(b, q * 4 + 3, bf));
        __builtin_nontemporal_store(r, (vfloat4*)&out[node * 8 + q]);
    }
}

// ---------- Layers 2/3: gather RAW x rows; dis_src from deg packed in csr. ----------
template<int DO_TS4>
__global__ __launch_bounds__(256) void k_aggz(const float4* __restrict__ xin,
                                              const int* __restrict__ rs,
                                              const int* __restrict__ re,
                                              const int* __restrict__ csr,
                                              const float* __restrict__ dis,
                                              const void* __restrict__ W,
                                              const void* __restrict__ b,
                                              const void* __restrict__ w4,
                                              const int* __restrict__ flagp,
                                              float* __restrict__ xout,
                                              float* __restrict__ ts4) {
    __shared__ float Wl[1024];
    __shared__ float W4l[32];
    __shared__ float Z[4][32];
    int tid = threadIdx.x;
    int bf = *flagp;
    if (bf) {
        ushort4 h = ((const ushort4*)W)[tid];
        int p = tid * 4;
        Wl[p] = u2f(h.x); Wl[p + 1] = u2f(h.y); Wl[p + 2] = u2f(h.z); Wl[p + 3] = u2f(h.w);
    } else {
        float4 v = ((const float4*)W)[tid];
        int p = tid * 4;
        Wl[p] = v.x; Wl[p + 1] = v.y; Wl[p + 2] = v.z; Wl[p + 3] = v.w;
    }
    if (DO_TS4 && tid < 32) W4l[tid] = LD(w4, tid, bf);

    int wid = tid >> 6;
    int node = blockIdx.x * 4 + wid;
    int lane = tid & 63;
    int q   = lane & 7;
    int grp = lane >> 3;
    int s = rs[node], e = re[node];
    float4 a0 = make_float4(0.f, 0.f, 0.f, 0.f);
    float4 a1 = a0, a2 = a0, a3 = a0;
    int i = s + grp;
    for (; i + 24 < e; i += 32) {
        int p0 = csr[i], p1 = csr[i + 8], p2 = csr[i + 16], p3 = csr[i + 24];
        int v0 = p0 & 0x1FFFF, v1 = p1 & 0x1FFFF, v2 = p2 & 0x1FFFF, v3 = p3 & 0x1FFFF;
        float d0 = rsqrtf((float)(p0 >> 17) + 1.0f);
        float d1 = rsqrtf((float)(p1 >> 17) + 1.0f);
        float d2 = rsqrtf((float)(p2 >> 17) + 1.0f);
        float d3 = rsqrtf((float)(p3 >> 17) + 1.0f);
        float4 m0 = xin[v0 * 8 + q];
        float4 m1 = xin[v1 * 8 + q];
        float4 m2 = xin[v2 * 8 + q];
        float4 m3 = xin[v3 * 8 + q];
        a0.x += d0 * m0.x; a0.y += d0 * m0.y; a0.z += d0 * m0.z; a0.w += d0 * m0.w;
        a1.x += d1 * m1.x; a1.y += d1 * m1.y; a1.z += d1 * m1.z; a1.w += d1 * m1.w;
        a2.x += d2 * m2.x; a2.y += d2 * m2.y; a2.z += d2 * m2.z; a2.w += d2 * m2.w;
        a3.x += d3 * m3.x; a3.y += d3 * m3.y; a3.z += d3 * m3.z; a3.w += d3 * m3.w;
    }
    for (; i < e; i += 8) {
        int pv = csr[i];
        int v = pv & 0x1FFFF;
        float dv = rsqrtf((float)(pv >> 17) + 1.0f);
        float4 m = xin[v * 8 + q];
        a0.x += dv * m.x; a0.y += dv * m.y; a0.z += dv * m.z; a0.w += dv * m.w;
    }
    float4 acc;
    acc.x = (a0.x + a1.x) + (a2.x + a3.x);
    acc.y = (a0.y + a1.y) + (a2.y + a3.y);
    acc.z = (a0.z + a1.z) + (a2.z + a3.z);
    acc.w = (a0.w + a1.w) + (a2.w + a3.w);
#pragma unroll
    for (int off = 8; off < 64; off <<= 1) {
        acc.x += __shfl_xor(acc.x, off);
        acc.y += __shfl_xor(acc.y, off);
        acc.z += __shfl_xor(acc.z, off);
        acc.w += __shfl_xor(acc.w, off);
    }
    if (grp == 0) {
        float4 self = xin[node * 8 + q];
        float di = dis[node];
        Z[wid][q * 4 + 0] = acc.x + di * self.x;
        Z[wid][q * 4 + 1] = acc.y + di * self.y;
        Z[wid][q * 4 + 2] = acc.z + di * self.z;
        Z[wid][q * 4 + 3] = acc.w + di * self.w;
    }
    __syncthreads();
    // ---- post-gather mm: x_out = tanh(dis*(Z@W)+b) ----
    int nd = tid >> 6;                 // node slot 0..3
    int col = tid & 31;
    int kbase = (tid & 32) >> 1;       // 0 or 16
    const float* zr = Z[nd];
    float a = 0.f;
#pragma unroll
    for (int k2 = 0; k2 < 16; k2++) a += zr[kbase + k2] * Wl[(kbase + k2) * 32 + col];
    a += __shfl_xor(a, 32);            // both halves now hold full dot
    int n2 = blockIdx.x * 4 + nd;
    float di2 = dis[n2];
    float xo = tanhf(di2 * a + LD(b, col, bf));
    if (!(tid & 32)) xout[n2 * 32 + col] = xo;
    if (DO_TS4) {
        float t4 = xo * W4l[col];      // identical in both halves
#pragma unroll
        for (int off = 1; off < 32; off <<= 1) t4 += __shfl_xor(t4, off);
        if ((tid & 63) == 0) ts4[n2] = di2 * t4;
    }
}

// 16 lanes per node.
__global__ __launch_bounds__(256) void k_agg1(const float* __restrict__ ts4,
                                              const int* __restrict__ rs,
                                              const int* __restrict__ re,
                                              const int* __restrict__ csr,
                                              const float* __restrict__ dis,
                                              const void* __restrict__ b4,
                                              const int* __restrict__ flagp,
                                              float* __restrict__ x4) {
    int node = blockIdx.x * 16 + (threadIdx.x >> 4);
    int lane = threadIdx.x & 15;
    int s = rs[node], e = re[node];
    float acc = 0.f;
    for (int i = s + lane; i < e; i += 16) acc += ts4[csr[i] & 0x1FFFF];
#pragma unroll
    for (int off = 1; off < 16; off <<= 1) acc += __shfl_xor(acc, off);
    if (lane == 0) {
        int bf = *flagp;
        x4[node] = tanhf(dis[node] * (acc + ts4[node]) + LD(b4, 0, bf));
    }
}

// ---------- Fused SortPooling + CNN/MLP head ----------
// Per graph block: stage keys in LDS, compute ranks in-block (same predicate as
// the old k_rank => identical selection), gather the KTOP x 97 pooled rows
// directly into LDS P (stride 100 for aligned float4 conv5 reads), then run the
// head. Deletes k_rank, k_pool, the Pg buffer (24 MB round-trip) and sel memset.
// All FMA chains keep sequential order => numerics unchanged.
__global__ __launch_bounds__(256) void k_head(
    const float* __restrict__ x1, const float* __restrict__ x2,
    const float* __restrict__ x3, const float* __restrict__ x4,
    const int* __restrict__ gstart,
    const void* __restrict__ w5, const void* __restrict__ b5,
    const void* __restrict__ w6, const void* __restrict__ b6,
    const void* __restrict__ f1w, const void* __restrict__ f1b,
    const void* __restrict__ f2w, const void* __restrict__ f2b,
    const int* __restrict__ flagp, void* __restrict__ out) {
    __shared__ float P[KTOP * 100];       // stride 100: 16B-aligned rows
    __shared__ float W5[16 * 100];
    __shared__ float W6[32 * 16 * 5];
    __shared__ float H5[16][30];
    __shared__ float M[16][15];
    __shared__ float H6[352];
    __shared__ float Rp[256];
    __shared__ float R1[128];
    __shared__ float keys[GMAX];
    __shared__ int   selL[KTOP];
    __shared__ float L[10];
    __shared__ float mls;
    int g = blockIdx.x;
    int tid = threadIdx.x;
    int bf = *flagp;
    int s = gstart[g], e = gstart[g + 1];
    int gsize = e - s;
    int gl = gsize < GMAX ? gsize : GMAX;

    if (tid < KTOP) selL[tid] = -1;
    for (int i = tid; i < gl; i += 256) keys[i] = x4[s + i];
    // stage weights (stride-100 for W5)
    for (int i = tid; i < 16 * 97; i += 256) {
        int o = i / 97, f = i - o * 97;
        W5[o * 100 + f] = LD(w5, i, bf);
    }
    if (bf) {
        const ushort4* w6v = (const ushort4*)w6;
        for (int i = tid; i < 640; i += 256) {           // 2560 = 640*4
            ushort4 h = w6v[i];
            int p = i * 4;
            W6[p] = u2f(h.x); W6[p + 1] = u2f(h.y); W6[p + 2] = u2f(h.z); W6[p + 3] = u2f(h.w);
        }
    } else {
        for (int i = tid; i < 2560; i += 256) W6[i] = ((const float*)w6)[i];
    }
    __syncthreads();
    // ---- rank (old k_rank, in-block) ----
    for (int li = tid; li < gsize; li += 256) {
        float ki = (li < GMAX) ? keys[li] : x4[s + li];
        int rank = 0;
        for (int j = 0; j < gl; j++) {
            float kj = keys[j];
            rank += (kj > ki) || (kj == ki && j < li);
        }
        for (int j = GMAX; j < gsize; j++) {             // never taken in practice
            float kj = x4[s + j];
            rank += (kj > ki) || (kj == ki && j < li);
        }
        if (rank < KTOP) selL[rank] = s + li;
    }
    __syncthreads();
    // ---- pooled gather (old k_pool, in-block) ----
    for (int idx = tid; idx < KTOP * 97; idx += 256) {
        int p = idx / 97, f = idx - p * 97;
        int v = selL[p];
        float val = 0.f;
        if (v >= 0) {
            if (f < 32)      val = x1[v * 32 + f];
            else if (f < 64) val = x2[v * 32 + f - 32];
            else if (f < 96) val = x3[v * 32 + f - 64];
            else             val = x4[v];
        }
        P[p * 100 + f] = val;
    }
    __syncthreads();
    // ---- conv5 + relu (float4 LDS reads; sequential adds keep FP order) ----
    for (int idx = tid; idx < 480; idx += 256) {
        int o = idx / 30, p = idx - o * 30;
        float acc = LD(b5, o, bf);
        const float* pr = &P[p * 100];
        const float* wr = &W5[o * 100];
#pragma unroll 6
        for (int f4 = 0; f4 < 24; f4++) {
            float4 a = *(const float4*)(pr + f4 * 4);
            float4 b = *(const float4*)(wr + f4 * 4);
            acc += b.x * a.x; acc += b.y * a.y; acc += b.z * a.z; acc += b.w * a.w;
        }
        acc += wr[96] * pr[96];
        H5[o][p] = fmaxf(acc, 0.f);
    }
    __syncthreads();
    for (int idx = tid; idx < 240; idx += 256) {   // maxpool2
        int o = idx / 15, q = idx - o * 15;
        M[o][q] = fmaxf(H5[o][2 * q], H5[o][2 * q + 1]);
    }
    __syncthreads();
    for (int idx = tid; idx < 352; idx += 256) {   // conv6 + relu
        int oc = idx / 11, tp = idx - oc * 11;
        float acc = LD(b6, oc, bf);
        const float* wr = &W6[oc * 80];
        for (int ic = 0; ic < 16; ic++) {
#pragma unroll
            for (int k = 0; k < 5; k++)
                acc += wr[ic * 5 + k] * M[ic][tp + k];
        }
        H6[idx] = fmaxf(acc, 0.f);
    }
    __syncthreads();
    {   // fc1: 2 threads per output column, 176 terms each, single accumulator
        int half = tid >> 7, col = tid & 127;
        int base = half * 176;
        float a = 0.f;
        for (int i = 0; i < 176; i++) {
            int ii = base + i;
            a += H6[ii] * LD(f1w, ii * 128 + col, bf);
        }
        Rp[tid] = a;
    }
    __syncthreads();
    if (tid < 128) R1[tid] = fmaxf(LD(f1b, tid, bf) + Rp[tid] + Rp[128 + tid], 0.f);
    __syncthreads();
    if (tid < 10) {   // fc2
        float acc = LD(f2b, tid, bf);
        for (int k = 0; k < 128; k++) acc += R1[k] * LD(f2w, k * 10 + tid, bf);
        L[tid] = acc;
    }
    __syncthreads();
    if (tid == 0) {
        float m = L[0];
        for (int c = 1; c < 10; c++) m = fmaxf(m, L[c]);
        float ssum = 0.f;
        for (int c = 0; c < 10; c++) ssum += expf(L[c] - m);
        mls = m + logf(ssum);
    }
    __syncthreads();
    if (tid < 10) {
        float v = L[tid] - mls;
        if (bf) ((bf16*)out)[g * 10 + tid] = __float2bfloat16(v);
        else    ((float*)out)[g * 10 + tid] = v;
    }
}

extern "C" void kernel_launch(void* const* d_in, const int* in_sizes, int n_in,
                              void* d_out, int out_size, void* d_ws, size_t ws_size,
                              hipStream_t stream) {
    const void* x   = d_in[0];
    const void* w1  = d_in[1];  const void* b1  = d_in[2];
    const void* w2  = d_in[3];  const void* b2  = d_in[4];
    const void* w3  = d_in[5];  const void* b3  = d_in[6];
    const void* w4  = d_in[7];  const void* b4  = d_in[8];
    const void* w5  = d_in[9];  const void* b5  = d_in[10];
    const void* w6  = d_in[11]; const void* b6  = d_in[12];
    const void* f1w = d_in[13]; const void* f1b = d_in[14];
    const void* f2w = d_in[15]; const void* f2b = d_in[16];
    const int* esrc  = (const int*)d_in[17];
    const int* edst  = (const int*)d_in[18];
    const int* batch = (const int*)d_in[19];

    char* w = (char*)d_ws;
    size_t off = 0;
    auto alloc = [&](size_t bytes) {
        void* p = w + off;
        off += (bytes + 255) & ~(size_t)255;
        return p;
    };
    int*   flag   = (int*)  alloc(256);
    int*   rs     = (int*)  alloc((size_t)N_NODES * 4);
    int*   re     = (int*)  alloc((size_t)N_NODES * 4);
    float* dis    = (float*)alloc((size_t)N_NODES * 4);
    int*   deg    = (int*)  alloc((size_t)N_NODES * 4);
    int*   csr    = (int*)  alloc((size_t)NBKT * BKT_CAP * 4);
    float* t      = (float*)alloc((size_t)N_NODES * 32 * 4);   // ts1 (aliased by ebuf head)
    float* x1     = (float*)alloc((size_t)N_NODES * 32 * 4);
    float* x2     = (float*)alloc((size_t)N_NODES * 32 * 4);
    float* x3     = (float*)alloc((size_t)N_NODES * 32 * 4);
    float* x4     = (float*)alloc((size_t)N_NODES * 4);
    float* ts4b   = (float*)alloc((size_t)N_NODES * 4);
    int*   gstart = (int*)  alloc((size_t)(NGRAPH + 1) * 4);
    int*   cur    = (int*)  alloc((size_t)NBKT * 4);
    (void)ws_size; (void)n_in; (void)in_sizes; (void)out_size;

    // ebuf (padded bucketed packed edges, 14.8 MB) aliases t + head of x1,
    // both dead until k_mm1 / k_agg layer 1.
    int* ebuf = (int*)t;

    int mb64 = (N_NODES + MM1_B - 1) / MM1_B;
    int ab   = N_NODES / 4;
    int a1b  = N_NODES / 16;

    k_detect<<<1, 64, 0, stream>>>(w1, flag);
    k_icur<<<(NBKT + 255) / 256, 256, 0, stream>>>(cur);
    k_scat<<<NTILE, 256, 0, stream>>>(esrc, edst, cur, ebuf);
    k_bcnt<<<NBKT, 256, 0, stream>>>(ebuf, cur, rs, re, dis, deg);
    k_bfill<<<NBKT, 256, 0, stream>>>(ebuf, cur, rs, deg, csr);
    k_gstart<<<5, 256, 0, stream>>>(batch, gstart);

    k_mm1<<<mb64, 256, 0, stream>>>(x, w1, flag, dis, t);
    // layer1: gather ts1 -> x1
    k_agg<<<ab, 256, 0, stream>>>((const float4*)t, rs, re, csr, dis, b1, flag, (float4*)x1);
    // layer2: gather x1 (deg-packed dis) -> z ; x2 = tanh(dis*(z@w2)+b2)
    k_aggz<0><<<ab, 256, 0, stream>>>((const float4*)x1, rs, re, csr, dis, w2, b2, w4, flag, x2, ts4b);
    // layer3: gather x2 -> z ; x3 = tanh(dis*(z@w3)+b3) ; ts4 = dis*(x3@w4)
    k_aggz<1><<<ab, 256, 0, stream>>>((const float4*)x2, rs, re, csr, dis, w3, b3, w4, flag, x3, ts4b);
    k_agg1<<<a1b, 256, 0, stream>>>(ts4b, rs, re, csr, dis, b4, flag, x4);
    k_head<<<NGRAPH, 256, 0, stream>>>(x1, x2, x3, x4, gstart,
                                       w5, b5, w6, b6,
                                       f1w, f1b, f2w, f2b, flag, (void*)d_out);
}